// Round 16
// baseline (128.248 us; speedup 1.0000x reference)
//
#include <hip/hip_runtime.h>
#include <hip/hip_bf16.h>
#include <stdint.h>

#define DEV static __device__ __forceinline__

typedef __attribute__((ext_vector_type(8))) __bf16 bf16x8;
typedef __attribute__((ext_vector_type(4))) __bf16 bf16x4;
typedef __attribute__((ext_vector_type(4))) float f32x4;
typedef __attribute__((ext_vector_type(16))) float f32x16;

// B=2, T=2048, C=1024, NH=16, HS=64
#define BB 2
#define TT 2048
#define CC 1024
#define NHH 16
#define HSS 64
#define BT 4096
#define N3 3072

DEV unsigned short f2bf(float f) {
  union { float f; uint32_t u; } v; v.f = f;
  uint32_t r = v.u + 0x7FFFu + ((v.u >> 16) & 1u);
  return (unsigned short)(r >> 16);
}

typedef const __attribute__((address_space(1))) unsigned int* gas_t;
typedef __attribute__((address_space(3))) unsigned int* las_t;

DEV void glds16(const void* g, void* l) {
  __builtin_amdgcn_global_load_lds((gas_t)g, (las_t)l, 16, 0, 0);
}

DEV f32x4 mfma16(bf16x8 a, bf16x8 b, f32x4 c) {
  return __builtin_amdgcn_mfma_f32_16x16x32_bf16(a, b, c, 0, 0, 0);
}
DEV f32x16 mfma32(bf16x8 a, bf16x8 b, f32x16 c) {
  return __builtin_amdgcn_mfma_f32_32x32x16_bf16(a, b, c, 0, 0, 0);
}

DEV bf16x8 ld8(const unsigned short* p) { return *(const bf16x8*)p; }

DEV f32x16 z16() {
  f32x16 v;
#pragma unroll
  for (int i = 0; i < 16; i++) v[i] = 0.f;
  return v;
}

// ---------- fused prep: x conv (blocks 0..1023) + W_attn transp (1024..4095)
// + W_proj transp (4096..5119). 256 threads/block.
__global__ __launch_bounds__(256) void k_prep(const float* __restrict__ x,
                                              const float* __restrict__ Wa,
                                              const float* __restrict__ Wp,
                                              unsigned short* __restrict__ xb,
                                              unsigned short* __restrict__ wabt,
                                              unsigned short* __restrict__ wpbt) {
  const int bid = blockIdx.x;
  const int t = threadIdx.x;
  if (bid < 1024) {
    int i = bid * 256 + t;
    const int n4 = BT * CC / 4;
#pragma unroll
    for (int r = 0; r < 4; r++, i += 262144) {
      if (i < n4) {
        float4 v = ((const float4*)x)[i];
        ushort4 o;
        o.x = f2bf(v.x); o.y = f2bf(v.y); o.z = f2bf(v.z); o.w = f2bf(v.w);
        ((ushort4*)xb)[i] = o;
      }
    }
    return;
  }
  __shared__ float tile[32][33];
  const float* in;
  unsigned short* out;
  int N, tid;
  if (bid < 4096) { in = Wa; out = wabt; N = N3; tid = bid - 1024; }
  else            { in = Wp; out = wpbt; N = CC; tid = bid - 4096; }
  const int ntx = N / 32;
  const int n0 = (tid % ntx) * 32, k0 = (tid / ntx) * 32;
  const int tx = t & 31, ty = t >> 5;
  for (int r = ty; r < 32; r += 8)
    tile[r][tx] = in[(size_t)(k0 + r) * N + n0 + tx];
  __syncthreads();
  for (int r = ty; r < 32; r += 8)
    out[(size_t)(n0 + r) * CC + k0 + tx] = f2bf(tile[tx][r]);
}

// ---------- GEMM: A[M][K] bf16, Bt[N][K] bf16, bias f32[N] ----------
// 128x128 tile, BK=32, 8 waves (2M x 4N, 64x32 per wave), ring-3 LDS (48KB),
// depth-2 prefetch + counted vmcnt. XCD-region decode. When vtOut != nullptr
// and the tile is in the V third (n0 >= 2048), the epilogue writes the
// per-head transposed V layout vt[bh][d][t] directly (replaces k_vt).
template <int OUT_BF16>
__global__ __launch_bounds__(512) void k_gemm(const unsigned short* __restrict__ A,
                                              const unsigned short* __restrict__ Bt,
                                              const float* __restrict__ bias,
                                              void* __restrict__ Cout,
                                              unsigned short* __restrict__ vtOut,
                                              int N, int K, int Rm, int Rn, int Xn) {
  __shared__ __align__(16) unsigned short As[3][128 * 32];
  __shared__ __align__(16) unsigned short Bs[3][128 * 32];
  const int t = threadIdx.x;
  const int wave = t >> 6, l = t & 63, lr = l & 15, lg = l >> 4;
  const int xcd = (int)blockIdx.x & 7, q = (int)blockIdx.x >> 3;
  const int m0 = ((xcd / Xn) * Rm + (q % Rm)) * 128;
  const int n0 = ((xcd % Xn) * Rn + (q / Rm)) * 128;
  const int wm = wave >> 2, wn = wave & 3;

  f32x4 acc[4][2] = {};

  const unsigned short* gA = A + (size_t)(m0 + (t >> 2)) * K + (t & 3) * 8;
  const unsigned short* gB = Bt + (size_t)(n0 + (t >> 2)) * K + (t & 3) * 8;

#define GSTAGE(buf_, k_)                                                  \
  do {                                                                    \
    glds16(gA + (k_), (char*)As[buf_] + t * 16);                          \
    glds16(gB + (k_), (char*)Bs[buf_] + t * 16);                          \
  } while (0)

  const int nst = K >> 5;
  GSTAGE(0, 0);
  GSTAGE(1, 32);

  for (int st = 0; st < nst; ++st) {
    __builtin_amdgcn_s_barrier();          // A: guards slot (st+2)%3 overwrite
    __builtin_amdgcn_sched_barrier(0);
    if (st + 2 < nst) GSTAGE((st + 2) % 3, (st + 2) * 32);
    __builtin_amdgcn_sched_barrier(0);
    if (st + 2 < nst)      asm volatile("s_waitcnt vmcnt(4)" ::: "memory");
    else if (st + 1 < nst) asm volatile("s_waitcnt vmcnt(2)" ::: "memory");
    else                   asm volatile("s_waitcnt vmcnt(0)" ::: "memory");
    __builtin_amdgcn_s_barrier();          // B: all waves' stage(st) visible
    __builtin_amdgcn_sched_barrier(0);

    const unsigned short* Ab = As[st % 3];
    const unsigned short* Bb = Bs[st % 3];
    bf16x8 av[4], bv[2];
#pragma unroll
    for (int i = 0; i < 4; i++)
      av[i] = ld8(Ab + (wm * 64 + i * 16 + lr) * 32 + lg * 8);
#pragma unroll
    for (int j = 0; j < 2; j++)
      bv[j] = ld8(Bb + (wn * 32 + j * 16 + lr) * 32 + lg * 8);
    __builtin_amdgcn_s_setprio(1);
#pragma unroll
    for (int i = 0; i < 4; i++)
#pragma unroll
      for (int j = 0; j < 2; j++)
        acc[i][j] = mfma16(av[i], bv[j], acc[i][j]);
    __builtin_amdgcn_s_setprio(0);
  }
#undef GSTAGE

  if (OUT_BF16 && vtOut != nullptr && n0 >= 2 * CC) {
    // V third: write vt[bh][d][t] directly (b=row>>11, t=row&2047)
#pragma unroll
    for (int j2 = 0; j2 < 2; j2++) {
      int cv = n0 - 2 * CC + wn * 32 + j2 * 16 + lr;  // h*64 + d
      int h = cv >> 6, d = cv & 63;
      float bv_ = bias[2 * CC + cv];
#pragma unroll
      for (int i = 0; i < 4; i++) {
        int row = m0 + wm * 64 + i * 16 + lg * 4;
        int bb = row >> 11, t2 = row & 2047;
        ushort4 wv;
        wv.x = f2bf(acc[i][j2][0] + bv_);
        wv.y = f2bf(acc[i][j2][1] + bv_);
        wv.z = f2bf(acc[i][j2][2] + bv_);
        wv.w = f2bf(acc[i][j2][3] + bv_);
        *(ushort4*)(vtOut + (((size_t)(bb * NHH + h) * HSS + d) << 11) + t2) = wv;
      }
    }
    return;
  }

#pragma unroll
  for (int j2 = 0; j2 < 2; j2++) {
    int col = n0 + wn * 32 + j2 * 16 + lr;
    float bv_ = bias[col];
#pragma unroll
    for (int i = 0; i < 4; i++) {
      int row = m0 + wm * 64 + i * 16 + lg * 4;
#pragma unroll
      for (int r = 0; r < 4; r++) {
        float v = acc[i][j2][r] + bv_;
        if (OUT_BF16)
          ((unsigned short*)Cout)[(size_t)(row + r) * N + col] = f2bf(v);
        else
          ((float*)Cout)[(size_t)(row + r) * N + col] = v;
      }
    }
  }
}

// ---------- flash attention: 8 waves, kv-parity split, paired q-tiles ----------
// 256 blocks x 8 waves. Block = (bh, p): segment A = q-tile 15-p, then B = p.
// Wave = (qsub 0..3, par 0..1). K staged in ring-2 LDS (stage AFTER barrier A,
// counted vmcnt(2), barrier B -> overwrite-safe); V read directly from global
// vt (L1/L2-resident; 4 qsub waves share rows -> L1 hits). LDS 66KB ->
// 2 blocks/CU, 4 waves/SIMD. Parity merge through Ps at segment end.
__global__ __launch_bounds__(512) void k_attn(const unsigned short* __restrict__ qkv,
                                              const unsigned short* __restrict__ vt,
                                              unsigned short* __restrict__ y) {
  __shared__ __align__(16) unsigned short Ks[2][128 * 64];
  __shared__ __align__(16) unsigned short Ps[8][32 * 64];
  __shared__ float Msh[4][64];
  __shared__ float Lsh[4][64];
  const int t = threadIdx.x;
  const int w = t >> 6, l = t & 63, lq = l & 31, hl = l >> 5;
  const int qsub = w & 3, par = w >> 2;
  const int id = blockIdx.x;
  const int bh = (id & 7) + 8 * ((id >> 3) & 3);
  const int p = id >> 5;  // 0..7
  const int b = bh >> 4, head = bh & 15;
  const int jA = 15 - p, jB = p;
  const int mA = jA + 1;        // + (jB+1) = 17 macro-steps
  const int NT = 17;
  const float cexp = 0.18033688011112042f;  // (1/8)*log2(e)
  const float THR = 40.0f;

#define SWZ(r_) ((((r_) & 7) ^ (((r_) >> 3) & 3)) << 4)

  const int myswz = SWZ(lq);
  int offs[4];
#pragma unroll
  for (int s = 0; s < 4; s++) offs[s] = (32 * s + 16 * hl) ^ myswz;

  // K staging: two glds16 issues; linear LDS off = i*8192 + w*1024 + l*16
  const int off0 = w * 1024 + l * 16;
  const int off1 = 8192 + w * 1024 + l * 16;
  const int rk0 = off0 >> 7, rk1 = off1 >> 7;          // K rows 0..127
  const int ck0 = (off0 & 127) ^ SWZ(rk0), ck1 = (off1 & 127) ^ SWZ(rk1);
  const char* gK0 = (const char*)(qkv + (size_t)(b * TT + rk0) * N3 + CC + head * HSS) + ck0;
  const char* gK1 = (const char*)(qkv + (size_t)(b * TT + rk1) * N3 + CC + head * HSS) + ck1;
  const int dK0 = w * 1024, dK1 = 8192 + w * 1024;

  // V global row bases: V^T row d = lq (and 32+lq)
  const unsigned short* vgA = vt + ((size_t)bh * HSS + lq) * TT;
  const unsigned short* vgB = vgA + (size_t)32 * TT;

#define STAGE(slot_, kvt_)                                                \
  do {                                                                    \
    size_t kb = (size_t)(kvt_) * (128 * N3 * 2);                          \
    glds16(gK0 + kb, (char*)Ks[slot_] + dK0);                             \
    glds16(gK1 + kb, (char*)Ks[slot_] + dK1);                             \
  } while (0)

#define WRITE_OUT()                                                       \
  do {                                                                    \
    float l_q = l_ln + __shfl_xor(l_ln, 32);                              \
    float inv = 1.0f / l_q;                                               \
    unsigned short* ybase = y + (size_t)(b * TT + q0w + lq) * CC + head * HSS; \
    _Pragma("unroll")                                                     \
    for (int g = 0; g < 4; g++) {                                         \
      ushort4 wv;                                                         \
      wv.x = f2bf(oa[4 * g + 0] * inv); wv.y = f2bf(oa[4 * g + 1] * inv); \
      wv.z = f2bf(oa[4 * g + 2] * inv); wv.w = f2bf(oa[4 * g + 3] * inv); \
      *(ushort4*)(ybase + 8 * g + 4 * hl) = wv;                           \
      ushort4 wv2;                                                        \
      wv2.x = f2bf(ob[4 * g + 0] * inv); wv2.y = f2bf(ob[4 * g + 1] * inv); \
      wv2.z = f2bf(ob[4 * g + 2] * inv); wv2.w = f2bf(ob[4 * g + 3] * inv); \
      *(ushort4*)(ybase + 32 + 8 * g + 4 * hl) = wv2;                     \
    }                                                                     \
  } while (0)

// cross-parity merge: par1 writes (oa,ob,m,l) through Ps; par0 combines + stores y
#define MERGE()                                                           \
  do {                                                                    \
    __builtin_amdgcn_s_barrier();                                         \
    if (par) {                                                            \
      float* poa = (float*)Ps[w];                                         \
      float* pob = (float*)Ps[w - 4];                                     \
      _Pragma("unroll")                                                   \
      for (int g = 0; g < 16; g++) { poa[g * 64 + l] = oa[g]; pob[g * 64 + l] = ob[g]; } \
      Msh[qsub][l] = m_s; Lsh[qsub][l] = l_ln;                            \
    }                                                                     \
    asm volatile("s_waitcnt lgkmcnt(0)" ::: "memory");                    \
    __builtin_amdgcn_s_barrier();                                         \
    __builtin_amdgcn_sched_barrier(0);                                    \
    if (!par) {                                                           \
      float m1 = Msh[qsub][l], l1 = Lsh[qsub][l];                         \
      float mstar = fmaxf(m_s, m1);                                       \
      float a0 = __builtin_amdgcn_exp2f((m_s - mstar) * cexp);            \
      float a1 = __builtin_amdgcn_exp2f((m1 - mstar) * cexp);             \
      const float* poa = (const float*)Ps[w + 4];                         \
      const float* pob = (const float*)Ps[w];                             \
      _Pragma("unroll")                                                   \
      for (int g = 0; g < 16; g++) {                                      \
        oa[g] = oa[g] * a0 + poa[g * 64 + l] * a1;                        \
        ob[g] = ob[g] * a0 + pob[g * 64 + l] * a1;                        \
      }                                                                   \
      l_ln = l_ln * a0 + l1 * a1;                                         \
      WRITE_OUT();                                                        \
    }                                                                     \
    __builtin_amdgcn_s_barrier();                                         \
  } while (0)

  // segment A state
  int q0w = jA * 128 + qsub * 32;
  const unsigned short* qp = qkv + (size_t)(b * TT + q0w + lq) * N3 + head * HSS + hl * 8;
  bf16x8 qf0 = ld8(qp), qf1 = ld8(qp + 16), qf2 = ld8(qp + 32), qf3 = ld8(qp + 48);
  float m_s = -INFINITY, l_ln = 0.f;
  f32x16 oa = z16(), ob = z16();
  char* prow = (char*)Ps[w] + lq * 128;

  STAGE(0, 0);

  for (int seq = 0; seq < NT; ++seq) {
    if (seq == mA) {
      MERGE();  // finalize segment A; y written by par0 (stage(mA) lands meanwhile)
      q0w = jB * 128 + qsub * 32;
      const unsigned short* qp2 = qkv + (size_t)(b * TT + q0w + lq) * N3 + head * HSS + hl * 8;
      qf0 = ld8(qp2); qf1 = ld8(qp2 + 16); qf2 = ld8(qp2 + 32); qf3 = ld8(qp2 + 48);
      m_s = -INFINITY; l_ln = 0.f;
      oa = z16(); ob = z16();
    }

    __builtin_amdgcn_s_barrier();            // A: all waves done with step seq-1
    __builtin_amdgcn_sched_barrier(0);
    if (seq + 1 < NT) {
      int s2 = seq + 1;
      int kvt2 = (s2 < mA) ? s2 : (s2 - mA);
      STAGE(s2 & 1, kvt2);                   // slot (seq+1)&1: safe post-barrier
    }
    __builtin_amdgcn_sched_barrier(0);
    if (seq + 1 < NT) asm volatile("s_waitcnt vmcnt(2)" ::: "memory");
    else              asm volatile("s_waitcnt vmcnt(0)" ::: "memory");
    __builtin_amdgcn_s_barrier();            // B: stage(seq) visible to all waves
    __builtin_amdgcn_sched_barrier(0);

    const int kvt = (seq < mA) ? seq : (seq - mA);
    const int kv0w = kvt * 128 + 64 * par;
    if (kv0w > q0w + 31) continue;  // fully-masked for this wave (barriers done)

    const unsigned short* Kb = Ks[seq & 1];

    // QK^T swapped: sa/sb hold S^T[kv][q=lq], kv=kv0w+(g&3)+8*(g>>2)+4*hl (+32 sb)
    const char* krA = (const char*)Kb + (64 * par + lq) * 128;
    const char* krB = krA + 32 * 128;
    f32x16 sa = z16(), sb = z16();
    __builtin_amdgcn_s_setprio(1);
    {
      bf16x8 ka, kb8;
      ka = ld8((const unsigned short*)(krA + offs[0]));
      kb8 = ld8((const unsigned short*)(krB + offs[0]));
      sa = mfma32(ka, qf0, sa); sb = mfma32(kb8, qf0, sb);
      ka = ld8((const unsigned short*)(krA + offs[1]));
      kb8 = ld8((const unsigned short*)(krB + offs[1]));
      sa = mfma32(ka, qf1, sa); sb = mfma32(kb8, qf1, sb);
      ka = ld8((const unsigned short*)(krA + offs[2]));
      kb8 = ld8((const unsigned short*)(krB + offs[2]));
      sa = mfma32(ka, qf2, sa); sb = mfma32(kb8, qf2, sb);
      ka = ld8((const unsigned short*)(krA + offs[3]));
      kb8 = ld8((const unsigned short*)(krB + offs[3]));
      sa = mfma32(ka, qf3, sa); sb = mfma32(kb8, qf3, sb);
    }
    __builtin_amdgcn_s_setprio(0);

    // causal mask near the diagonal
    if (kv0w + 63 > q0w) {
      const int q = q0w + lq;
#pragma unroll
      for (int g = 0; g < 16; g++) {
        int kvl = kv0w + (g & 3) + 8 * (g >> 2) + 4 * hl;
        if (kvl > q) sa[g] = -INFINITY;
        if (kvl + 32 > q) sb[g] = -INFINITY;
      }
    }

    // per-lane max + cross-half combine
    float tmax = -INFINITY;
#pragma unroll
    for (int g = 0; g < 16; g++) tmax = fmaxf(tmax, fmaxf(sa[g], sb[g]));
    tmax = fmaxf(tmax, __shfl_xor(tmax, 32));

    if (!__all(tmax <= m_s + THR)) {
      float m_new = fmaxf(m_s, tmax);
      float alpha = __builtin_amdgcn_exp2f((m_s - m_new) * cexp);
      l_ln *= alpha;
#pragma unroll
      for (int g = 0; g < 16; g++) { oa[g] *= alpha; ob[g] *= alpha; }
      m_s = m_new;
    }

    // exp in place; accumulate per-lane l
    const float mc = m_s * cexp;
    float tsum = 0.f;
#pragma unroll
    for (int g = 0; g < 16; g++) {
      sa[g] = __builtin_amdgcn_exp2f(__builtin_fmaf(sa[g], cexp, -mc));
      sb[g] = __builtin_amdgcn_exp2f(__builtin_fmaf(sb[g], cexp, -mc));
      tsum += sa[g] + sb[g];
    }
    l_ln += tsum;

    // P -> LDS bounce (wave-private)
#pragma unroll
    for (int u2 = 0; u2 < 4; u2++) {
      bf16x4 w0, w1;
#pragma unroll
      for (int r = 0; r < 4; r++) { w0[r] = (__bf16)sa[4 * u2 + r]; w1[r] = (__bf16)sb[4 * u2 + r]; }
      *(bf16x4*)(prow + ((16 * u2 + 8 * hl) ^ myswz)) = w0;
      *(bf16x4*)(prow + ((64 + 16 * u2 + 8 * hl) ^ myswz)) = w1;
    }
    asm volatile("s_waitcnt lgkmcnt(0)" ::: "memory");
    __builtin_amdgcn_sched_barrier(0);
    bf16x8 pf0 = ld8((const unsigned short*)(prow + offs[0]));
    bf16x8 pf1 = ld8((const unsigned short*)(prow + offs[1]));
    bf16x8 pf2 = ld8((const unsigned short*)(prow + offs[2]));
    bf16x8 pf3 = ld8((const unsigned short*)(prow + offs[3]));

    // PV on this wave's 64-kv parity half; V rows lq / lq+32 read from GLOBAL
    // vt (L1/L2-resident). va element j = V^T[d][kv0w + 16s + 8hl + j].
    const unsigned short* vA = vgA + kv0w + 8 * hl;
    const unsigned short* vB = vgB + kv0w + 8 * hl;
    __builtin_amdgcn_s_setprio(1);
    {
      bf16x8 va, vb8;
      va = ld8(vA);       vb8 = ld8(vB);
      oa = mfma32(va, pf0, oa); ob = mfma32(vb8, pf0, ob);
      va = ld8(vA + 16);  vb8 = ld8(vB + 16);
      oa = mfma32(va, pf1, oa); ob = mfma32(vb8, pf1, ob);
      va = ld8(vA + 32);  vb8 = ld8(vB + 32);
      oa = mfma32(va, pf2, oa); ob = mfma32(vb8, pf2, ob);
      va = ld8(vA + 48);  vb8 = ld8(vB + 48);
      oa = mfma32(va, pf3, oa); ob = mfma32(vb8, pf3, ob);
    }
    __builtin_amdgcn_s_setprio(0);
    __builtin_amdgcn_sched_barrier(0);  // fence: keep V-loads inside this step
  }

  MERGE();  // finalize segment B
#undef STAGE
#undef WRITE_OUT
#undef MERGE
#undef SWZ
}

extern "C" void kernel_launch(void* const* d_in, const int* in_sizes, int n_in,
                              void* d_out, int out_size, void* d_ws, size_t ws_size,
                              hipStream_t stream) {
  const float* x = (const float*)d_in[0];
  const float* W_attn = (const float*)d_in[1];
  const float* b_attn = (const float*)d_in[2];
  const float* W_proj = (const float*)d_in[3];
  const float* b_proj = (const float*)d_in[4];

  char* ws = (char*)d_ws;
  unsigned short* xb   = (unsigned short*)(ws);                       // 8 MB
  unsigned short* wabt = (unsigned short*)(ws + 8388608);             // 6 MB  [3072][1024]
  unsigned short* wpbt = (unsigned short*)(ws + 14680064);            // 2 MB  [1024][1024]
  unsigned short* qkvb = (unsigned short*)(ws + 16777216);            // 24 MB [4096][3072]
  unsigned short* vt   = (unsigned short*)(ws + 41943040);            // 8 MB  [32][64][2048]
  unsigned short* yb   = (unsigned short*)(ws + 50331648);            // 8 MB  [4096][1024]

  k_prep<<<dim3(5120), 256, 0, stream>>>(x, W_attn, W_proj, xb, wabt, wpbt);
  // QKV: M=4096, N=3072 -> 32x24 tiles = 768 blocks; XCD grid 4x2, region 8Mx12N
  // V third written transposed to vt directly (k_vt fused into epilogue).
  k_gemm<1><<<dim3(768), 512, 0, stream>>>(xb, wabt, b_attn, qkvb, vt, N3, CC, 8, 12, 2);
  k_attn<<<dim3(256), 512, 0, stream>>>(qkvb, vt, yb);
  // proj: M=4096, N=1024 -> 32x8 tiles = 256 blocks; XCD grid 8x1, region 4Mx8N
  k_gemm<0><<<dim3(256), 512, 0, stream>>>(yb, wpbt, b_proj, d_out, nullptr, CC, CC, 4, 8, 1);
}

// Round 17
// 113.705 us; speedup vs baseline: 1.1279x; 1.1279x over previous
//
#include <hip/hip_runtime.h>
#include <hip/hip_bf16.h>
#include <stdint.h>

#define DEV static __device__ __forceinline__

typedef __attribute__((ext_vector_type(8))) __bf16 bf16x8;
typedef __attribute__((ext_vector_type(4))) __bf16 bf16x4;
typedef __attribute__((ext_vector_type(4))) float f32x4;
typedef __attribute__((ext_vector_type(16))) float f32x16;

// B=2, T=2048, C=1024, NH=16, HS=64
#define BB 2
#define TT 2048
#define CC 1024
#define NHH 16
#define HSS 64
#define BT 4096
#define N3 3072

DEV unsigned short f2bf(float f) {
  union { float f; uint32_t u; } v; v.f = f;
  uint32_t r = v.u + 0x7FFFu + ((v.u >> 16) & 1u);
  return (unsigned short)(r >> 16);
}

typedef const __attribute__((address_space(1))) unsigned int* gas_t;
typedef __attribute__((address_space(3))) unsigned int* las_t;

DEV void glds16(const void* g, void* l) {
  __builtin_amdgcn_global_load_lds((gas_t)g, (las_t)l, 16, 0, 0);
}

DEV f32x4 mfma16(bf16x8 a, bf16x8 b, f32x4 c) {
  return __builtin_amdgcn_mfma_f32_16x16x32_bf16(a, b, c, 0, 0, 0);
}
DEV f32x16 mfma32(bf16x8 a, bf16x8 b, f32x16 c) {
  return __builtin_amdgcn_mfma_f32_32x32x16_bf16(a, b, c, 0, 0, 0);
}

DEV bf16x8 ld8(const unsigned short* p) { return *(const bf16x8*)p; }

DEV f32x16 z16() {
  f32x16 v;
#pragma unroll
  for (int i = 0; i < 16; i++) v[i] = 0.f;
  return v;
}

// ---------- fused prep: x conv (blocks 0..1023) + W_attn transp (1024..4095)
// + W_proj transp (4096..5119). 256 threads/block.
__global__ __launch_bounds__(256) void k_prep(const float* __restrict__ x,
                                              const float* __restrict__ Wa,
                                              const float* __restrict__ Wp,
                                              unsigned short* __restrict__ xb,
                                              unsigned short* __restrict__ wabt,
                                              unsigned short* __restrict__ wpbt) {
  const int bid = blockIdx.x;
  const int t = threadIdx.x;
  if (bid < 1024) {
    int i = bid * 256 + t;
    const int n4 = BT * CC / 4;
#pragma unroll
    for (int r = 0; r < 4; r++, i += 262144) {
      if (i < n4) {
        float4 v = ((const float4*)x)[i];
        ushort4 o;
        o.x = f2bf(v.x); o.y = f2bf(v.y); o.z = f2bf(v.z); o.w = f2bf(v.w);
        ((ushort4*)xb)[i] = o;
      }
    }
    return;
  }
  __shared__ float tile[32][33];
  const float* in;
  unsigned short* out;
  int N, tid;
  if (bid < 4096) { in = Wa; out = wabt; N = N3; tid = bid - 1024; }
  else            { in = Wp; out = wpbt; N = CC; tid = bid - 4096; }
  const int ntx = N / 32;
  const int n0 = (tid % ntx) * 32, k0 = (tid / ntx) * 32;
  const int tx = t & 31, ty = t >> 5;
  for (int r = ty; r < 32; r += 8)
    tile[r][tx] = in[(size_t)(k0 + r) * N + n0 + tx];
  __syncthreads();
  for (int r = ty; r < 32; r += 8)
    out[(size_t)(n0 + r) * CC + k0 + tx] = f2bf(tile[tx][r]);
}

// ---------- GEMM: A[M][K] bf16, Bt[N][K] bf16, bias f32[N] ----------
// 128x128 tile, BK=32, 8 waves (2M x 4N, 64x32 per wave), ring-3 LDS (48KB),
// depth-2 prefetch + counted vmcnt. XCD-region decode. When vtOut != nullptr
// and the tile is in the V third (n0 >= 2048), the epilogue writes the
// per-head transposed V layout vt[bh][d][t] directly (replaces k_vt).
template <int OUT_BF16>
__global__ __launch_bounds__(512) void k_gemm(const unsigned short* __restrict__ A,
                                              const unsigned short* __restrict__ Bt,
                                              const float* __restrict__ bias,
                                              void* __restrict__ Cout,
                                              unsigned short* __restrict__ vtOut,
                                              int N, int K, int Rm, int Rn, int Xn) {
  __shared__ __align__(16) unsigned short As[3][128 * 32];
  __shared__ __align__(16) unsigned short Bs[3][128 * 32];
  const int t = threadIdx.x;
  const int wave = t >> 6, l = t & 63, lr = l & 15, lg = l >> 4;
  const int xcd = (int)blockIdx.x & 7, q = (int)blockIdx.x >> 3;
  const int m0 = ((xcd / Xn) * Rm + (q % Rm)) * 128;
  const int n0 = ((xcd % Xn) * Rn + (q / Rm)) * 128;
  const int wm = wave >> 2, wn = wave & 3;

  f32x4 acc[4][2] = {};

  const unsigned short* gA = A + (size_t)(m0 + (t >> 2)) * K + (t & 3) * 8;
  const unsigned short* gB = Bt + (size_t)(n0 + (t >> 2)) * K + (t & 3) * 8;

#define GSTAGE(buf_, k_)                                                  \
  do {                                                                    \
    glds16(gA + (k_), (char*)As[buf_] + t * 16);                          \
    glds16(gB + (k_), (char*)Bs[buf_] + t * 16);                          \
  } while (0)

  const int nst = K >> 5;
  GSTAGE(0, 0);
  GSTAGE(1, 32);

  for (int st = 0; st < nst; ++st) {
    __builtin_amdgcn_s_barrier();          // A: guards slot (st+2)%3 overwrite
    __builtin_amdgcn_sched_barrier(0);
    if (st + 2 < nst) GSTAGE((st + 2) % 3, (st + 2) * 32);
    __builtin_amdgcn_sched_barrier(0);
    if (st + 2 < nst)      asm volatile("s_waitcnt vmcnt(4)" ::: "memory");
    else if (st + 1 < nst) asm volatile("s_waitcnt vmcnt(2)" ::: "memory");
    else                   asm volatile("s_waitcnt vmcnt(0)" ::: "memory");
    __builtin_amdgcn_s_barrier();          // B: all waves' stage(st) visible
    __builtin_amdgcn_sched_barrier(0);

    const unsigned short* Ab = As[st % 3];
    const unsigned short* Bb = Bs[st % 3];
    bf16x8 av[4], bv[2];
#pragma unroll
    for (int i = 0; i < 4; i++)
      av[i] = ld8(Ab + (wm * 64 + i * 16 + lr) * 32 + lg * 8);
#pragma unroll
    for (int j = 0; j < 2; j++)
      bv[j] = ld8(Bb + (wn * 32 + j * 16 + lr) * 32 + lg * 8);
    __builtin_amdgcn_s_setprio(1);
#pragma unroll
    for (int i = 0; i < 4; i++)
#pragma unroll
      for (int j = 0; j < 2; j++)
        acc[i][j] = mfma16(av[i], bv[j], acc[i][j]);
    __builtin_amdgcn_s_setprio(0);
  }
#undef GSTAGE

  if (OUT_BF16 && vtOut != nullptr && n0 >= 2 * CC) {
    // V third: write vt[bh][d][t] directly (b=row>>11, t=row&2047)
#pragma unroll
    for (int j2 = 0; j2 < 2; j2++) {
      int cv = n0 - 2 * CC + wn * 32 + j2 * 16 + lr;  // h*64 + d
      int h = cv >> 6, d = cv & 63;
      float bv_ = bias[2 * CC + cv];
#pragma unroll
      for (int i = 0; i < 4; i++) {
        int row = m0 + wm * 64 + i * 16 + lg * 4;
        int bb = row >> 11, t2 = row & 2047;
        ushort4 wv;
        wv.x = f2bf(acc[i][j2][0] + bv_);
        wv.y = f2bf(acc[i][j2][1] + bv_);
        wv.z = f2bf(acc[i][j2][2] + bv_);
        wv.w = f2bf(acc[i][j2][3] + bv_);
        *(ushort4*)(vtOut + (((size_t)(bb * NHH + h) * HSS + d) << 11) + t2) = wv;
      }
    }
    return;
  }

#pragma unroll
  for (int j2 = 0; j2 < 2; j2++) {
    int col = n0 + wn * 32 + j2 * 16 + lr;
    float bv_ = bias[col];
#pragma unroll
    for (int i = 0; i < 4; i++) {
      int row = m0 + wm * 64 + i * 16 + lg * 4;
#pragma unroll
      for (int r = 0; r < 4; r++) {
        float v = acc[i][j2][r] + bv_;
        if (OUT_BF16)
          ((unsigned short*)Cout)[(size_t)(row + r) * N + col] = f2bf(v);
        else
          ((float*)Cout)[(size_t)(row + r) * N + col] = v;
      }
    }
  }
}

// ---------- flash attention: 512 blocks x 4 waves, 2 blocks/CU ----------
// Block = (bh, pp, qh): segment A = q-tile 15-pp rows [qh*64,qh*64+64), then
// B = q-tile pp same rows -> 17 macro-steps of 128 kv, uniform. Wave =
// (qsub 0/1, par 0/1): 32 q-rows x 64-kv parity half. K and V both in ring-2
// LDS (stage issued AFTER barrier A into the slot freed by step seq-1;
// counted vmcnt(8) waits the PREVIOUS stage -> one full step to land).
// Ps 16KB P-bounce; merge m/l scratch overlaid on the dead K ring slot.
// LDS = 80KB exactly -> 2 independent blocks/CU (barrier decoupling).
__global__ __launch_bounds__(256) void k_attn(const unsigned short* __restrict__ qkv,
                                              const unsigned short* __restrict__ vt,
                                              unsigned short* __restrict__ y) {
  __shared__ __align__(16) unsigned short Ks[2][128 * 64];
  __shared__ __align__(16) unsigned short Vs[2][128 * 64];
  __shared__ __align__(16) unsigned short Ps[4][32 * 64];
  const int t = threadIdx.x;
  const int w = t >> 6, l = t & 63, lq = l & 31, hl = l >> 5;
  const int qsub = w & 1, par = w >> 1;
  const int id = blockIdx.x;
  const int bh = (id & 7) + 8 * ((id >> 3) & 3);
  const int uu = id >> 5;            // 0..15
  const int pp = uu & 7, qh = uu >> 3;
  const int b = bh >> 4, head = bh & 15;
  const int jA = 15 - pp, jB = pp;
  const int mA = jA + 1;             // + (jB+1) = 17
  const int NT = 17;
  const int fsA = (mA & 1) ^ 1;      // dead K slot during segment-A merge
  const float cexp = 0.18033688011112042f;  // (1/8)*log2(e)
  const float THR = 40.0f;

#define SWZ(r_) ((((r_) & 7) ^ (((r_) >> 3) & 3)) << 4)

  const int myswz = SWZ(lq);
  int offs[4];
#pragma unroll
  for (int s = 0; s < 4; s++) offs[s] = (32 * s + 16 * hl) ^ myswz;

  // staging: 4 issues per array; linear LDS off_i = i*4096 + w*1024 + l*16
  const char* gK[4];
  const char* gV[4];
  int dL[4];
#pragma unroll
  for (int i = 0; i < 4; i++) {
    int off = i * 4096 + w * 1024 + l * 16;
    int rk = off >> 7;                       // K row 0..127 (kv)
    int ck = (off & 127) ^ SWZ(rk);
    int rv = rk & 63, half = rk >> 6;        // V^T row d, kv half
    int cv = (off & 127) ^ SWZ(rv);
    gK[i] = (const char*)(qkv + (size_t)(b * TT + rk) * N3 + CC + head * HSS) + ck;
    gV[i] = (const char*)(vt + ((size_t)bh * HSS + rv) * TT + half * 64) + cv;
    dL[i] = i * 4096 + w * 1024;
  }

#define STAGE(slot_, kvt_)                                                \
  do {                                                                    \
    size_t kb = (size_t)(kvt_) * (128 * N3 * 2);                          \
    size_t vb = (size_t)(kvt_) * 256;                                     \
    _Pragma("unroll")                                                     \
    for (int i_ = 0; i_ < 4; i_++) {                                      \
      glds16(gK[i_] + kb, (char*)Ks[slot_] + dL[i_]);                     \
      glds16(gV[i_] + vb, (char*)Vs[slot_] + dL[i_]);                     \
    }                                                                     \
  } while (0)

#define WRITE_OUT()                                                       \
  do {                                                                    \
    float l_q = l_ln + __shfl_xor(l_ln, 32);                              \
    float inv = 1.0f / l_q;                                               \
    unsigned short* ybase = y + (size_t)(b * TT + q0w + lq) * CC + head * HSS; \
    _Pragma("unroll")                                                     \
    for (int g = 0; g < 4; g++) {                                         \
      ushort4 wv;                                                         \
      wv.x = f2bf(oa[4 * g + 0] * inv); wv.y = f2bf(oa[4 * g + 1] * inv); \
      wv.z = f2bf(oa[4 * g + 2] * inv); wv.w = f2bf(oa[4 * g + 3] * inv); \
      *(ushort4*)(ybase + 8 * g + 4 * hl) = wv;                           \
      ushort4 wv2;                                                        \
      wv2.x = f2bf(ob[4 * g + 0] * inv); wv2.y = f2bf(ob[4 * g + 1] * inv); \
      wv2.z = f2bf(ob[4 * g + 2] * inv); wv2.w = f2bf(ob[4 * g + 3] * inv); \
      *(ushort4*)(ybase + 32 + 8 * g + 4 * hl) = wv2;                     \
    }                                                                     \
  } while (0)

// parity merge: par1 writes oa/ob to Ps, m/l to the dead K slot fs_;
// par0 combines + stores y.
#define MERGE(fs_)                                                        \
  do {                                                                    \
    __builtin_amdgcn_s_barrier();                                         \
    float* poolK = (float*)Ks[fs_];                                       \
    float* poa = (float*)Ps[qsub * 2];                                    \
    float* pob = (float*)Ps[qsub * 2 + 1];                                \
    if (par) {                                                            \
      _Pragma("unroll")                                                   \
      for (int g = 0; g < 16; g++) { poa[g * 64 + l] = oa[g]; pob[g * 64 + l] = ob[g]; } \
      poolK[qsub * 64 + l] = m_s;                                         \
      poolK[128 + qsub * 64 + l] = l_ln;                                  \
    }                                                                     \
    asm volatile("s_waitcnt lgkmcnt(0)" ::: "memory");                    \
    __builtin_amdgcn_s_barrier();                                         \
    __builtin_amdgcn_sched_barrier(0);                                    \
    if (!par) {                                                           \
      float m1 = poolK[qsub * 64 + l], l1 = poolK[128 + qsub * 64 + l];   \
      float mstar = fmaxf(m_s, m1);                                       \
      float a0 = __builtin_amdgcn_exp2f((m_s - mstar) * cexp);            \
      float a1 = __builtin_amdgcn_exp2f((m1 - mstar) * cexp);             \
      _Pragma("unroll")                                                   \
      for (int g = 0; g < 16; g++) {                                      \
        oa[g] = oa[g] * a0 + poa[g * 64 + l] * a1;                        \
        ob[g] = ob[g] * a0 + pob[g * 64 + l] * a1;                        \
      }                                                                   \
      l_ln = l_ln * a0 + l1 * a1;                                         \
      WRITE_OUT();                                                        \
    }                                                                     \
    __builtin_amdgcn_s_barrier();                                         \
  } while (0)

  // segment A state
  int q0w = jA * 128 + qh * 64 + qsub * 32;
  const unsigned short* qp = qkv + (size_t)(b * TT + q0w + lq) * N3 + head * HSS + hl * 8;
  bf16x8 qf0 = ld8(qp), qf1 = ld8(qp + 16), qf2 = ld8(qp + 32), qf3 = ld8(qp + 48);
  float m_s = -INFINITY, l_ln = 0.f;
  f32x16 oa = z16(), ob = z16();
  char* prow = (char*)Ps[w] + lq * 128;

  STAGE(0, 0);

  for (int seq = 0; seq < NT; ++seq) {
    if (seq == mA) {
      MERGE(fsA);  // finalize segment A (stage(mA) in flight in slot mA&1)
      q0w = jB * 128 + qh * 64 + qsub * 32;
      const unsigned short* qp2 = qkv + (size_t)(b * TT + q0w + lq) * N3 + head * HSS + hl * 8;
      qf0 = ld8(qp2); qf1 = ld8(qp2 + 16); qf2 = ld8(qp2 + 32); qf3 = ld8(qp2 + 48);
      m_s = -INFINITY; l_ln = 0.f;
      oa = z16(); ob = z16();
    }

    __builtin_amdgcn_s_barrier();            // A: all waves done with step seq-1
    __builtin_amdgcn_sched_barrier(0);
    if (seq + 1 < NT) {
      int s2 = seq + 1;
      int kvt2 = (s2 < mA) ? s2 : (s2 - mA);
      STAGE(s2 & 1, kvt2);                   // slot freed at barrier A
    }
    __builtin_amdgcn_sched_barrier(0);
    if (seq + 1 < NT) asm volatile("s_waitcnt vmcnt(8)" ::: "memory");
    else              asm volatile("s_waitcnt vmcnt(0)" ::: "memory");
    __builtin_amdgcn_s_barrier();            // B: stage(seq) visible to all waves
    __builtin_amdgcn_sched_barrier(0);

    const int kvt = (seq < mA) ? seq : (seq - mA);
    const int kv0w = kvt * 128 + 64 * par;
    if (kv0w > q0w + 31) continue;  // fully-masked for this wave (barriers done)

    const unsigned short* Kb = Ks[seq & 1];
    const unsigned short* Vb = Vs[seq & 1];

    // QK^T swapped: sa/sb hold S^T[kv][q=lq], kv=kv0w+(g&3)+8*(g>>2)+4*hl (+32 sb)
    const char* krA = (const char*)Kb + (64 * par + lq) * 128;
    const char* krB = krA + 32 * 128;
    f32x16 sa = z16(), sb = z16();
    __builtin_amdgcn_s_setprio(1);
    {
      bf16x8 ka, kb8;
      ka = ld8((const unsigned short*)(krA + offs[0]));
      kb8 = ld8((const unsigned short*)(krB + offs[0]));
      sa = mfma32(ka, qf0, sa); sb = mfma32(kb8, qf0, sb);
      ka = ld8((const unsigned short*)(krA + offs[1]));
      kb8 = ld8((const unsigned short*)(krB + offs[1]));
      sa = mfma32(ka, qf1, sa); sb = mfma32(kb8, qf1, sb);
      ka = ld8((const unsigned short*)(krA + offs[2]));
      kb8 = ld8((const unsigned short*)(krB + offs[2]));
      sa = mfma32(ka, qf2, sa); sb = mfma32(kb8, qf2, sb);
      ka = ld8((const unsigned short*)(krA + offs[3]));
      kb8 = ld8((const unsigned short*)(krB + offs[3]));
      sa = mfma32(ka, qf3, sa); sb = mfma32(kb8, qf3, sb);
    }
    __builtin_amdgcn_s_setprio(0);

    // causal mask near the diagonal
    if (kv0w + 63 > q0w) {
      const int q = q0w + lq;
#pragma unroll
      for (int g = 0; g < 16; g++) {
        int kvl = kv0w + (g & 3) + 8 * (g >> 2) + 4 * hl;
        if (kvl > q) sa[g] = -INFINITY;
        if (kvl + 32 > q) sb[g] = -INFINITY;
      }
    }

    // per-lane max + cross-half combine
    float tmax = -INFINITY;
#pragma unroll
    for (int g = 0; g < 16; g++) tmax = fmaxf(tmax, fmaxf(sa[g], sb[g]));
    tmax = fmaxf(tmax, __shfl_xor(tmax, 32));

    if (!__all(tmax <= m_s + THR)) {
      float m_new = fmaxf(m_s, tmax);
      float alpha = __builtin_amdgcn_exp2f((m_s - m_new) * cexp);
      l_ln *= alpha;
#pragma unroll
      for (int g = 0; g < 16; g++) { oa[g] *= alpha; ob[g] *= alpha; }
      m_s = m_new;
    }

    // exp in place; accumulate per-lane l
    const float mc = m_s * cexp;
    float tsum = 0.f;
#pragma unroll
    for (int g = 0; g < 16; g++) {
      sa[g] = __builtin_amdgcn_exp2f(__builtin_fmaf(sa[g], cexp, -mc));
      sb[g] = __builtin_amdgcn_exp2f(__builtin_fmaf(sb[g], cexp, -mc));
      tsum += sa[g] + sb[g];
    }
    l_ln += tsum;

    // P -> LDS bounce (wave-private)
#pragma unroll
    for (int u2 = 0; u2 < 4; u2++) {
      bf16x4 w0, w1;
#pragma unroll
      for (int r = 0; r < 4; r++) { w0[r] = (__bf16)sa[4 * u2 + r]; w1[r] = (__bf16)sb[4 * u2 + r]; }
      *(bf16x4*)(prow + ((16 * u2 + 8 * hl) ^ myswz)) = w0;
      *(bf16x4*)(prow + ((64 + 16 * u2 + 8 * hl) ^ myswz)) = w1;
    }
    asm volatile("s_waitcnt lgkmcnt(0)" ::: "memory");
    __builtin_amdgcn_sched_barrier(0);
    bf16x8 pf0 = ld8((const unsigned short*)(prow + offs[0]));
    bf16x8 pf1 = ld8((const unsigned short*)(prow + offs[1]));
    bf16x8 pf2 = ld8((const unsigned short*)(prow + offs[2]));
    bf16x8 pf3 = ld8((const unsigned short*)(prow + offs[3]));

    // PV on this wave's V subtile (kv parity half)
    const char* vrA = (const char*)Vb + par * 8192 + lq * 128;
    const char* vrB = vrA + 32 * 128;
    __builtin_amdgcn_s_setprio(1);
    {
      bf16x8 va, vb8;
      va = ld8((const unsigned short*)(vrA + offs[0]));
      vb8 = ld8((const unsigned short*)(vrB + offs[0]));
      oa = mfma32(va, pf0, oa); ob = mfma32(vb8, pf0, ob);
      va = ld8((const unsigned short*)(vrA + offs[1]));
      vb8 = ld8((const unsigned short*)(vrB + offs[1]));
      oa = mfma32(va, pf1, oa); ob = mfma32(vb8, pf1, ob);
      va = ld8((const unsigned short*)(vrA + offs[2]));
      vb8 = ld8((const unsigned short*)(vrB + offs[2]));
      oa = mfma32(va, pf2, oa); ob = mfma32(vb8, pf2, ob);
      va = ld8((const unsigned short*)(vrA + offs[3]));
      vb8 = ld8((const unsigned short*)(vrB + offs[3]));
      oa = mfma32(va, pf3, oa); ob = mfma32(vb8, pf3, ob);
    }
    __builtin_amdgcn_s_setprio(0);
  }

  MERGE(1);  // finalize segment B (no staging in flight; both slots dead)
#undef STAGE
#undef WRITE_OUT
#undef MERGE
#undef SWZ
}

extern "C" void kernel_launch(void* const* d_in, const int* in_sizes, int n_in,
                              void* d_out, int out_size, void* d_ws, size_t ws_size,
                              hipStream_t stream) {
  const float* x = (const float*)d_in[0];
  const float* W_attn = (const float*)d_in[1];
  const float* b_attn = (const float*)d_in[2];
  const float* W_proj = (const float*)d_in[3];
  const float* b_proj = (const float*)d_in[4];

  char* ws = (char*)d_ws;
  unsigned short* xb   = (unsigned short*)(ws);                       // 8 MB
  unsigned short* wabt = (unsigned short*)(ws + 8388608);             // 6 MB  [3072][1024]
  unsigned short* wpbt = (unsigned short*)(ws + 14680064);            // 2 MB  [1024][1024]
  unsigned short* qkvb = (unsigned short*)(ws + 16777216);            // 24 MB [4096][3072]
  unsigned short* vt   = (unsigned short*)(ws + 41943040);            // 8 MB  [32][64][2048]
  unsigned short* yb   = (unsigned short*)(ws + 50331648);            // 8 MB  [4096][1024]

  k_prep<<<dim3(5120), 256, 0, stream>>>(x, W_attn, W_proj, xb, wabt, wpbt);
  // QKV: M=4096, N=3072 -> 32x24 tiles = 768 blocks; XCD grid 4x2, region 8Mx12N
  // V third written transposed to vt directly (k_vt fused into epilogue).
  k_gemm<1><<<dim3(768), 512, 0, stream>>>(xb, wabt, b_attn, qkvb, vt, N3, CC, 8, 12, 2);
  k_attn<<<dim3(512), 256, 0, stream>>>(qkvb, vt, yb);
  // proj: M=4096, N=1024 -> 32x8 tiles = 256 blocks; XCD grid 8x1, region 4Mx8N
  k_gemm<0><<<dim3(256), 512, 0, stream>>>(yb, wpbt, b_proj, d_out, nullptr, CC, CC, 4, 8, 1);
}

// Round 18
// 106.408 us; speedup vs baseline: 1.2052x; 1.0686x over previous
//
#include <hip/hip_runtime.h>
#include <hip/hip_bf16.h>
#include <stdint.h>

#define DEV static __device__ __forceinline__

typedef __attribute__((ext_vector_type(8))) __bf16 bf16x8;
typedef __attribute__((ext_vector_type(4))) __bf16 bf16x4;
typedef __attribute__((ext_vector_type(4))) float f32x4;
typedef __attribute__((ext_vector_type(16))) float f32x16;

// B=2, T=2048, C=1024, NH=16, HS=64
#define BB 2
#define TT 2048
#define CC 1024
#define NHH 16
#define HSS 64
#define BT 4096
#define N3 3072

DEV unsigned short f2bf(float f) {
  union { float f; uint32_t u; } v; v.f = f;
  uint32_t r = v.u + 0x7FFFu + ((v.u >> 16) & 1u);
  return (unsigned short)(r >> 16);
}

typedef const __attribute__((address_space(1))) unsigned int* gas_t;
typedef __attribute__((address_space(3))) unsigned int* las_t;

DEV void glds16(const void* g, void* l) {
  __builtin_amdgcn_global_load_lds((gas_t)g, (las_t)l, 16, 0, 0);
}

DEV f32x4 mfma16(bf16x8 a, bf16x8 b, f32x4 c) {
  return __builtin_amdgcn_mfma_f32_16x16x32_bf16(a, b, c, 0, 0, 0);
}
DEV f32x16 mfma32(bf16x8 a, bf16x8 b, f32x16 c) {
  return __builtin_amdgcn_mfma_f32_32x32x16_bf16(a, b, c, 0, 0, 0);
}

DEV bf16x8 ld8(const unsigned short* p) { return *(const bf16x8*)p; }

DEV f32x16 z16() {
  f32x16 v;
#pragma unroll
  for (int i = 0; i < 16; i++) v[i] = 0.f;
  return v;
}

// ---------- fused prep: x conv (blocks 0..1023) + W_attn transp (1024..4095)
// + W_proj transp (4096..5119). 256 threads/block.
__global__ __launch_bounds__(256) void k_prep(const float* __restrict__ x,
                                              const float* __restrict__ Wa,
                                              const float* __restrict__ Wp,
                                              unsigned short* __restrict__ xb,
                                              unsigned short* __restrict__ wabt,
                                              unsigned short* __restrict__ wpbt) {
  const int bid = blockIdx.x;
  const int t = threadIdx.x;
  if (bid < 1024) {
    int i = bid * 256 + t;
    const int n4 = BT * CC / 4;
#pragma unroll
    for (int r = 0; r < 4; r++, i += 262144) {
      if (i < n4) {
        float4 v = ((const float4*)x)[i];
        ushort4 o;
        o.x = f2bf(v.x); o.y = f2bf(v.y); o.z = f2bf(v.z); o.w = f2bf(v.w);
        ((ushort4*)xb)[i] = o;
      }
    }
    return;
  }
  __shared__ float tile[32][33];
  const float* in;
  unsigned short* out;
  int N, tid;
  if (bid < 4096) { in = Wa; out = wabt; N = N3; tid = bid - 1024; }
  else            { in = Wp; out = wpbt; N = CC; tid = bid - 4096; }
  const int ntx = N / 32;
  const int n0 = (tid % ntx) * 32, k0 = (tid / ntx) * 32;
  const int tx = t & 31, ty = t >> 5;
  for (int r = ty; r < 32; r += 8)
    tile[r][tx] = in[(size_t)(k0 + r) * N + n0 + tx];
  __syncthreads();
  for (int r = ty; r < 32; r += 8)
    out[(size_t)(n0 + r) * CC + k0 + tx] = f2bf(tile[tx][r]);
}

// ---------- GEMM: A[M][K] bf16, Bt[N][K] bf16, bias f32[N] ----------
// 128x128 tile, BK=32, 8 waves (2M x 4N, 64x32 per wave), ring-3 LDS (48KB),
// depth-2 prefetch + counted vmcnt. XCD-region decode. When vtOut != nullptr
// and the tile is in the V third (n0 >= 2048), the epilogue writes the
// per-head transposed V layout vt[bh][d][t] directly (replaces k_vt).
template <int OUT_BF16>
__global__ __launch_bounds__(512) void k_gemm(const unsigned short* __restrict__ A,
                                              const unsigned short* __restrict__ Bt,
                                              const float* __restrict__ bias,
                                              void* __restrict__ Cout,
                                              unsigned short* __restrict__ vtOut,
                                              int N, int K, int Rm, int Rn, int Xn) {
  __shared__ __align__(16) unsigned short As[3][128 * 32];
  __shared__ __align__(16) unsigned short Bs[3][128 * 32];
  const int t = threadIdx.x;
  const int wave = t >> 6, l = t & 63, lr = l & 15, lg = l >> 4;
  const int xcd = (int)blockIdx.x & 7, q = (int)blockIdx.x >> 3;
  const int m0 = ((xcd / Xn) * Rm + (q % Rm)) * 128;
  const int n0 = ((xcd % Xn) * Rn + (q / Rm)) * 128;
  const int wm = wave >> 2, wn = wave & 3;

  f32x4 acc[4][2] = {};

  const unsigned short* gA = A + (size_t)(m0 + (t >> 2)) * K + (t & 3) * 8;
  const unsigned short* gB = Bt + (size_t)(n0 + (t >> 2)) * K + (t & 3) * 8;

#define GSTAGE(buf_, k_)                                                  \
  do {                                                                    \
    glds16(gA + (k_), (char*)As[buf_] + t * 16);                          \
    glds16(gB + (k_), (char*)Bs[buf_] + t * 16);                          \
  } while (0)

  const int nst = K >> 5;
  GSTAGE(0, 0);
  GSTAGE(1, 32);

  for (int st = 0; st < nst; ++st) {
    __builtin_amdgcn_s_barrier();          // A: guards slot (st+2)%3 overwrite
    __builtin_amdgcn_sched_barrier(0);
    if (st + 2 < nst) GSTAGE((st + 2) % 3, (st + 2) * 32);
    __builtin_amdgcn_sched_barrier(0);
    if (st + 2 < nst)      asm volatile("s_waitcnt vmcnt(4)" ::: "memory");
    else if (st + 1 < nst) asm volatile("s_waitcnt vmcnt(2)" ::: "memory");
    else                   asm volatile("s_waitcnt vmcnt(0)" ::: "memory");
    __builtin_amdgcn_s_barrier();          // B: all waves' stage(st) visible
    __builtin_amdgcn_sched_barrier(0);

    const unsigned short* Ab = As[st % 3];
    const unsigned short* Bb = Bs[st % 3];
    bf16x8 av[4], bv[2];
#pragma unroll
    for (int i = 0; i < 4; i++)
      av[i] = ld8(Ab + (wm * 64 + i * 16 + lr) * 32 + lg * 8);
#pragma unroll
    for (int j = 0; j < 2; j++)
      bv[j] = ld8(Bb + (wn * 32 + j * 16 + lr) * 32 + lg * 8);
    __builtin_amdgcn_s_setprio(1);
#pragma unroll
    for (int i = 0; i < 4; i++)
#pragma unroll
      for (int j = 0; j < 2; j++)
        acc[i][j] = mfma16(av[i], bv[j], acc[i][j]);
    __builtin_amdgcn_s_setprio(0);
  }
#undef GSTAGE

  if (OUT_BF16 && vtOut != nullptr && n0 >= 2 * CC) {
    // V third: write vt[bh][d][t] directly (b=row>>11, t=row&2047)
#pragma unroll
    for (int j2 = 0; j2 < 2; j2++) {
      int cv = n0 - 2 * CC + wn * 32 + j2 * 16 + lr;  // h*64 + d
      int h = cv >> 6, d = cv & 63;
      float bv_ = bias[2 * CC + cv];
#pragma unroll
      for (int i = 0; i < 4; i++) {
        int row = m0 + wm * 64 + i * 16 + lg * 4;
        int bb = row >> 11, t2 = row & 2047;
        ushort4 wv;
        wv.x = f2bf(acc[i][j2][0] + bv_);
        wv.y = f2bf(acc[i][j2][1] + bv_);
        wv.z = f2bf(acc[i][j2][2] + bv_);
        wv.w = f2bf(acc[i][j2][3] + bv_);
        *(ushort4*)(vtOut + (((size_t)(bb * NHH + h) * HSS + d) << 11) + t2) = wv;
      }
    }
    return;
  }

#pragma unroll
  for (int j2 = 0; j2 < 2; j2++) {
    int col = n0 + wn * 32 + j2 * 16 + lr;
    float bv_ = bias[col];
#pragma unroll
    for (int i = 0; i < 4; i++) {
      int row = m0 + wm * 64 + i * 16 + lg * 4;
#pragma unroll
      for (int r = 0; r < 4; r++) {
        float v = acc[i][j2][r] + bv_;
        if (OUT_BF16)
          ((unsigned short*)Cout)[(size_t)(row + r) * N + col] = f2bf(v);
        else
          ((float*)Cout)[(size_t)(row + r) * N + col] = v;
      }
    }
  }
}

// ---------- flash attention: 8 waves, kv-parity split, paired q-tiles ----------
// (round-9 structure, proven 42us) 256 blocks x 8 waves. Block = (bh, p):
// segment A = q-tile 15-p, then B = p. Wave = (qsub 0..3, par 0..1). Ring-3
// K/V LDS, depth-1 prefetch + counted vmcnt(4). Parity merge through Ps.
__global__ __launch_bounds__(512) void k_attn(const unsigned short* __restrict__ qkv,
                                              const unsigned short* __restrict__ vt,
                                              unsigned short* __restrict__ y) {
  __shared__ __align__(16) unsigned short Ks[3][128 * 64];
  __shared__ __align__(16) unsigned short Vs[3][128 * 64];
  __shared__ __align__(16) unsigned short Ps[8][32 * 64];
  __shared__ float Msh[4][64];
  __shared__ float Lsh[4][64];
  const int t = threadIdx.x;
  const int w = t >> 6, l = t & 63, lq = l & 31, hl = l >> 5;
  const int qsub = w & 3, par = w >> 2;
  const int id = blockIdx.x;
  const int bh = (id & 7) + 8 * ((id >> 3) & 3);
  const int p = id >> 5;  // 0..7
  const int b = bh >> 4, head = bh & 15;
  const int jA = 15 - p, jB = p;
  const int mA = jA + 1;        // + (jB+1) = 17 macro-steps
  const int NT = 17;
  const float cexp = 0.18033688011112042f;  // (1/8)*log2(e)
  const float THR = 40.0f;

#define SWZ(r_) ((((r_) & 7) ^ (((r_) >> 3) & 3)) << 4)

  const int myswz = SWZ(lq);
  int offs[4];
#pragma unroll
  for (int s = 0; s < 4; s++) offs[s] = (32 * s + 16 * hl) ^ myswz;

  // staging: two glds16 issues per array; linear LDS off = i*8192 + w*1024 + l*16
  const int off0 = w * 1024 + l * 16;
  const int off1 = 8192 + w * 1024 + l * 16;
  const int rk0 = off0 >> 7, rk1 = off1 >> 7;          // K rows 0..127
  const int ck0 = (off0 & 127) ^ SWZ(rk0), ck1 = (off1 & 127) ^ SWZ(rk1);
  const int rv0 = rk0 & 63, rv1 = rk1 & 63;            // V rows 0..63, subtile = i
  const int cv0 = (off0 & 127) ^ SWZ(rv0), cv1 = (off1 & 127) ^ SWZ(rv1);
  const char* gK0 = (const char*)(qkv + (size_t)(b * TT + rk0) * N3 + CC + head * HSS) + ck0;
  const char* gK1 = (const char*)(qkv + (size_t)(b * TT + rk1) * N3 + CC + head * HSS) + ck1;
  const char* gV0 = (const char*)(vt + ((size_t)bh * HSS + rv0) * TT) + cv0;        // kv 0..63
  const char* gV1 = (const char*)(vt + ((size_t)bh * HSS + rv1) * TT + 64) + cv1;   // kv 64..127
  const int dK0 = w * 1024, dK1 = 8192 + w * 1024;

#define STAGE(slot_, kvt_)                                                \
  do {                                                                    \
    size_t kb = (size_t)(kvt_) * (128 * N3 * 2);                          \
    size_t vb = (size_t)(kvt_) * 256;                                     \
    glds16(gK0 + kb, (char*)Ks[slot_] + dK0);                             \
    glds16(gK1 + kb, (char*)Ks[slot_] + dK1);                             \
    glds16(gV0 + vb, (char*)Vs[slot_] + dK0);                             \
    glds16(gV1 + vb, (char*)Vs[slot_] + dK1);                             \
  } while (0)

#define WRITE_OUT()                                                       \
  do {                                                                    \
    float l_q = l_ln + __shfl_xor(l_ln, 32);                              \
    float inv = 1.0f / l_q;                                               \
    unsigned short* ybase = y + (size_t)(b * TT + q0w + lq) * CC + head * HSS; \
    _Pragma("unroll")                                                     \
    for (int g = 0; g < 4; g++) {                                         \
      ushort4 wv;                                                         \
      wv.x = f2bf(oa[4 * g + 0] * inv); wv.y = f2bf(oa[4 * g + 1] * inv); \
      wv.z = f2bf(oa[4 * g + 2] * inv); wv.w = f2bf(oa[4 * g + 3] * inv); \
      *(ushort4*)(ybase + 8 * g + 4 * hl) = wv;                           \
      ushort4 wv2;                                                        \
      wv2.x = f2bf(ob[4 * g + 0] * inv); wv2.y = f2bf(ob[4 * g + 1] * inv); \
      wv2.z = f2bf(ob[4 * g + 2] * inv); wv2.w = f2bf(ob[4 * g + 3] * inv); \
      *(ushort4*)(ybase + 32 + 8 * g + 4 * hl) = wv2;                     \
    }                                                                     \
  } while (0)

// cross-parity merge: par1 writes (oa,ob,m,l) through Ps; par0 combines + stores y
#define MERGE()                                                           \
  do {                                                                    \
    __builtin_amdgcn_s_barrier();                                         \
    if (par) {                                                            \
      float* poa = (float*)Ps[w];                                         \
      float* pob = (float*)Ps[w - 4];                                     \
      _Pragma("unroll")                                                   \
      for (int g = 0; g < 16; g++) { poa[g * 64 + l] = oa[g]; pob[g * 64 + l] = ob[g]; } \
      Msh[qsub][l] = m_s; Lsh[qsub][l] = l_ln;                            \
    }                                                                     \
    asm volatile("s_waitcnt lgkmcnt(0)" ::: "memory");                    \
    __builtin_amdgcn_s_barrier();                                         \
    __builtin_amdgcn_sched_barrier(0);                                    \
    if (!par) {                                                           \
      float m1 = Msh[qsub][l], l1 = Lsh[qsub][l];                         \
      float mstar = fmaxf(m_s, m1);                                       \
      float a0 = __builtin_amdgcn_exp2f((m_s - mstar) * cexp);            \
      float a1 = __builtin_amdgcn_exp2f((m1 - mstar) * cexp);             \
      const float* poa = (const float*)Ps[w + 4];                         \
      const float* pob = (const float*)Ps[w];                             \
      _Pragma("unroll")                                                   \
      for (int g = 0; g < 16; g++) {                                      \
        oa[g] = oa[g] * a0 + poa[g * 64 + l] * a1;                        \
        ob[g] = ob[g] * a0 + pob[g * 64 + l] * a1;                        \
      }                                                                   \
      l_ln = l_ln * a0 + l1 * a1;                                         \
      WRITE_OUT();                                                        \
    }                                                                     \
    __builtin_amdgcn_s_barrier();                                         \
  } while (0)

  // segment A state
  int q0w = jA * 128 + qsub * 32;
  const unsigned short* qp = qkv + (size_t)(b * TT + q0w + lq) * N3 + head * HSS + hl * 8;
  bf16x8 qf0 = ld8(qp), qf1 = ld8(qp + 16), qf2 = ld8(qp + 32), qf3 = ld8(qp + 48);
  float m_s = -INFINITY, l_ln = 0.f;
  f32x16 oa = z16(), ob = z16();
  char* prow = (char*)Ps[w] + lq * 128;

  STAGE(0, 0);
  int cur = 0;

  for (int seq = 0; seq < NT; ++seq) {
    if (seq == mA) {
      MERGE();  // finalize segment A; y written by par0
      q0w = jB * 128 + qsub * 32;
      const unsigned short* qp2 = qkv + (size_t)(b * TT + q0w + lq) * N3 + head * HSS + hl * 8;
      qf0 = ld8(qp2); qf1 = ld8(qp2 + 16); qf2 = ld8(qp2 + 32); qf3 = ld8(qp2 + 48);
      m_s = -INFINITY; l_ln = 0.f;
      oa = z16(); ob = z16();
    }

    const int kvt = (seq < mA) ? seq : (seq - mA);
    if (seq + 1 < NT) {
      int s2 = seq + 1;
      int kvt2 = (s2 < mA) ? s2 : (s2 - mA);
      int nxt = (cur == 2) ? 0 : cur + 1;
      STAGE(nxt, kvt2);
      __builtin_amdgcn_sched_barrier(0);
      asm volatile("s_waitcnt vmcnt(4)" ::: "memory");
    } else {
      asm volatile("s_waitcnt vmcnt(0)" ::: "memory");
    }
    __builtin_amdgcn_s_barrier();
    __builtin_amdgcn_sched_barrier(0);

    const int mybuf = cur;
    cur = (cur == 2) ? 0 : cur + 1;

    const int kv0w = kvt * 128 + 64 * par;
    if (kv0w > q0w + 31) continue;  // fully-masked for this wave (barriers done)

    const unsigned short* Kb = Ks[mybuf];
    const unsigned short* Vb = Vs[mybuf];

    // QK^T swapped: sa/sb hold S^T[kv][q=lq], kv=kv0w+(g&3)+8*(g>>2)+4*hl (+32 sb)
    const char* krA = (const char*)Kb + (64 * par + lq) * 128;
    const char* krB = krA + 32 * 128;
    f32x16 sa = z16(), sb = z16();
    __builtin_amdgcn_s_setprio(1);
    {
      bf16x8 ka, kb8;
      ka = ld8((const unsigned short*)(krA + offs[0]));
      kb8 = ld8((const unsigned short*)(krB + offs[0]));
      sa = mfma32(ka, qf0, sa); sb = mfma32(kb8, qf0, sb);
      ka = ld8((const unsigned short*)(krA + offs[1]));
      kb8 = ld8((const unsigned short*)(krB + offs[1]));
      sa = mfma32(ka, qf1, sa); sb = mfma32(kb8, qf1, sb);
      ka = ld8((const unsigned short*)(krA + offs[2]));
      kb8 = ld8((const unsigned short*)(krB + offs[2]));
      sa = mfma32(ka, qf2, sa); sb = mfma32(kb8, qf2, sb);
      ka = ld8((const unsigned short*)(krA + offs[3]));
      kb8 = ld8((const unsigned short*)(krB + offs[3]));
      sa = mfma32(ka, qf3, sa); sb = mfma32(kb8, qf3, sb);
    }
    __builtin_amdgcn_s_setprio(0);

    // causal mask near the diagonal
    if (kv0w + 63 > q0w) {
      const int q = q0w + lq;
#pragma unroll
      for (int g = 0; g < 16; g++) {
        int kvl = kv0w + (g & 3) + 8 * (g >> 2) + 4 * hl;
        if (kvl > q) sa[g] = -INFINITY;
        if (kvl + 32 > q) sb[g] = -INFINITY;
      }
    }

    // per-lane max + cross-half combine
    float tmax = -INFINITY;
#pragma unroll
    for (int g = 0; g < 16; g++) tmax = fmaxf(tmax, fmaxf(sa[g], sb[g]));
    tmax = fmaxf(tmax, __shfl_xor(tmax, 32));

    if (!__all(tmax <= m_s + THR)) {
      float m_new = fmaxf(m_s, tmax);
      float alpha = __builtin_amdgcn_exp2f((m_s - m_new) * cexp);
      l_ln *= alpha;
#pragma unroll
      for (int g = 0; g < 16; g++) { oa[g] *= alpha; ob[g] *= alpha; }
      m_s = m_new;
    }

    // exp in place; accumulate per-lane l
    const float mc = m_s * cexp;
    float tsum = 0.f;
#pragma unroll
    for (int g = 0; g < 16; g++) {
      sa[g] = __builtin_amdgcn_exp2f(__builtin_fmaf(sa[g], cexp, -mc));
      sb[g] = __builtin_amdgcn_exp2f(__builtin_fmaf(sb[g], cexp, -mc));
      tsum += sa[g] + sb[g];
    }
    l_ln += tsum;

    // P -> LDS bounce (wave-private)
#pragma unroll
    for (int u2 = 0; u2 < 4; u2++) {
      bf16x4 w0, w1;
#pragma unroll
      for (int r = 0; r < 4; r++) { w0[r] = (__bf16)sa[4 * u2 + r]; w1[r] = (__bf16)sb[4 * u2 + r]; }
      *(bf16x4*)(prow + ((16 * u2 + 8 * hl) ^ myswz)) = w0;
      *(bf16x4*)(prow + ((64 + 16 * u2 + 8 * hl) ^ myswz)) = w1;
    }
    asm volatile("s_waitcnt lgkmcnt(0)" ::: "memory");
    __builtin_amdgcn_sched_barrier(0);
    bf16x8 pf0 = ld8((const unsigned short*)(prow + offs[0]));
    bf16x8 pf1 = ld8((const unsigned short*)(prow + offs[1]));
    bf16x8 pf2 = ld8((const unsigned short*)(prow + offs[2]));
    bf16x8 pf3 = ld8((const unsigned short*)(prow + offs[3]));

    // PV on this wave's V subtile (kv parity half)
    const char* vrA = (const char*)Vb + par * 8192 + lq * 128;
    const char* vrB = vrA + 32 * 128;
    __builtin_amdgcn_s_setprio(1);
    {
      bf16x8 va, vb8;
      va = ld8((const unsigned short*)(vrA + offs[0]));
      vb8 = ld8((const unsigned short*)(vrB + offs[0]));
      oa = mfma32(va, pf0, oa); ob = mfma32(vb8, pf0, ob);
      va = ld8((const unsigned short*)(vrA + offs[1]));
      vb8 = ld8((const unsigned short*)(vrB + offs[1]));
      oa = mfma32(va, pf1, oa); ob = mfma32(vb8, pf1, ob);
      va = ld8((const unsigned short*)(vrA + offs[2]));
      vb8 = ld8((const unsigned short*)(vrB + offs[2]));
      oa = mfma32(va, pf2, oa); ob = mfma32(vb8, pf2, ob);
      va = ld8((const unsigned short*)(vrA + offs[3]));
      vb8 = ld8((const unsigned short*)(vrB + offs[3]));
      oa = mfma32(va, pf3, oa); ob = mfma32(vb8, pf3, ob);
    }
    __builtin_amdgcn_s_setprio(0);
  }

  MERGE();  // finalize segment B
#undef STAGE
#undef WRITE_OUT
#undef MERGE
#undef SWZ
}

extern "C" void kernel_launch(void* const* d_in, const int* in_sizes, int n_in,
                              void* d_out, int out_size, void* d_ws, size_t ws_size,
                              hipStream_t stream) {
  const float* x = (const float*)d_in[0];
  const float* W_attn = (const float*)d_in[1];
  const float* b_attn = (const float*)d_in[2];
  const float* W_proj = (const float*)d_in[3];
  const float* b_proj = (const float*)d_in[4];

  char* ws = (char*)d_ws;
  unsigned short* xb   = (unsigned short*)(ws);                       // 8 MB
  unsigned short* wabt = (unsigned short*)(ws + 8388608);             // 6 MB  [3072][1024]
  unsigned short* wpbt = (unsigned short*)(ws + 14680064);            // 2 MB  [1024][1024]
  unsigned short* qkvb = (unsigned short*)(ws + 16777216);            // 24 MB [4096][3072]
  unsigned short* vt   = (unsigned short*)(ws + 41943040);            // 8 MB  [32][64][2048]
  unsigned short* yb   = (unsigned short*)(ws + 50331648);            // 8 MB  [4096][1024]

  k_prep<<<dim3(5120), 256, 0, stream>>>(x, W_attn, W_proj, xb, wabt, wpbt);
  // QKV: M=4096, N=3072 -> 32x24 tiles = 768 blocks; XCD grid 4x2, region 8Mx12N
  // V third written transposed to vt directly (k_vt fused into epilogue).
  k_gemm<1><<<dim3(768), 512, 0, stream>>>(xb, wabt, b_attn, qkvb, vt, N3, CC, 8, 12, 2);
  k_attn<<<dim3(256), 512, 0, stream>>>(qkvb, vt, yb);
  // proj: M=4096, N=1024 -> 32x8 tiles = 256 blocks; XCD grid 8x1, region 4Mx8N
  k_gemm<0><<<dim3(256), 512, 0, stream>>>(yb, wpbt, b_proj, d_out, nullptr, CC, CC, 4, 8, 1);
}

// Round 19
// 105.697 us; speedup vs baseline: 1.2134x; 1.0067x over previous
//
#include <hip/hip_runtime.h>
#include <hip/hip_bf16.h>
#include <stdint.h>

#define DEV static __device__ __forceinline__

typedef __attribute__((ext_vector_type(8))) __bf16 bf16x8;
typedef __attribute__((ext_vector_type(4))) __bf16 bf16x4;
typedef __attribute__((ext_vector_type(4))) float f32x4;
typedef __attribute__((ext_vector_type(16))) float f32x16;

// B=2, T=2048, C=1024, NH=16, HS=64
#define BB 2
#define TT 2048
#define CC 1024
#define NHH 16
#define HSS 64
#define BT 4096
#define N3 3072

DEV unsigned short f2bf(float f) {
  union { float f; uint32_t u; } v; v.f = f;
  uint32_t r = v.u + 0x7FFFu + ((v.u >> 16) & 1u);
  return (unsigned short)(r >> 16);
}

typedef const __attribute__((address_space(1))) unsigned int* gas_t;
typedef __attribute__((address_space(3))) unsigned int* las_t;

DEV void glds16(const void* g, void* l) {
  __builtin_amdgcn_global_load_lds((gas_t)g, (las_t)l, 16, 0, 0);
}

DEV f32x4 mfma16(bf16x8 a, bf16x8 b, f32x4 c) {
  return __builtin_amdgcn_mfma_f32_16x16x32_bf16(a, b, c, 0, 0, 0);
}
DEV f32x16 mfma32(bf16x8 a, bf16x8 b, f32x16 c) {
  return __builtin_amdgcn_mfma_f32_32x32x16_bf16(a, b, c, 0, 0, 0);
}

DEV bf16x8 ld8(const unsigned short* p) { return *(const bf16x8*)p; }

DEV f32x16 z16() {
  f32x16 v;
#pragma unroll
  for (int i = 0; i < 16; i++) v[i] = 0.f;
  return v;
}

// ---------- fused prep: x conv (blocks 0..1023) + W_attn transp (1024..4095)
// + W_proj transp (4096..5119). 256 threads/block.
__global__ __launch_bounds__(256) void k_prep(const float* __restrict__ x,
                                              const float* __restrict__ Wa,
                                              const float* __restrict__ Wp,
                                              unsigned short* __restrict__ xb,
                                              unsigned short* __restrict__ wabt,
                                              unsigned short* __restrict__ wpbt) {
  const int bid = blockIdx.x;
  const int t = threadIdx.x;
  if (bid < 1024) {
    int i = bid * 256 + t;
    const int n4 = BT * CC / 4;
#pragma unroll
    for (int r = 0; r < 4; r++, i += 262144) {
      if (i < n4) {
        float4 v = ((const float4*)x)[i];
        ushort4 o;
        o.x = f2bf(v.x); o.y = f2bf(v.y); o.z = f2bf(v.z); o.w = f2bf(v.w);
        ((ushort4*)xb)[i] = o;
      }
    }
    return;
  }
  __shared__ float tile[32][33];
  const float* in;
  unsigned short* out;
  int N, tid;
  if (bid < 4096) { in = Wa; out = wabt; N = N3; tid = bid - 1024; }
  else            { in = Wp; out = wpbt; N = CC; tid = bid - 4096; }
  const int ntx = N / 32;
  const int n0 = (tid % ntx) * 32, k0 = (tid / ntx) * 32;
  const int tx = t & 31, ty = t >> 5;
  for (int r = ty; r < 32; r += 8)
    tile[r][tx] = in[(size_t)(k0 + r) * N + n0 + tx];
  __syncthreads();
  for (int r = ty; r < 32; r += 8)
    out[(size_t)(n0 + r) * CC + k0 + tx] = f2bf(tile[tx][r]);
}

// ---------- GEMM: A[M][K] bf16, Bt[N][K] bf16, bias f32[N] ----------
// 128x128 tile, BK=32, 8 waves (2M x 4N, 64x32 per wave), ring-3 LDS (48KB),
// depth-2 prefetch + counted vmcnt. XCD-region decode. When vtOut != nullptr
// and the tile is in the V third (n0 >= 2048), the epilogue writes the
// per-head transposed V layout vt[bh][d][t] directly (replaces k_vt).
template <int OUT_BF16>
__global__ __launch_bounds__(512) void k_gemm(const unsigned short* __restrict__ A,
                                              const unsigned short* __restrict__ Bt,
                                              const float* __restrict__ bias,
                                              void* __restrict__ Cout,
                                              unsigned short* __restrict__ vtOut,
                                              int N, int K, int Rm, int Rn, int Xn) {
  __shared__ __align__(16) unsigned short As[3][128 * 32];
  __shared__ __align__(16) unsigned short Bs[3][128 * 32];
  const int t = threadIdx.x;
  const int wave = t >> 6, l = t & 63, lr = l & 15, lg = l >> 4;
  const int xcd = (int)blockIdx.x & 7, q = (int)blockIdx.x >> 3;
  const int m0 = ((xcd / Xn) * Rm + (q % Rm)) * 128;
  const int n0 = ((xcd % Xn) * Rn + (q / Rm)) * 128;
  const int wm = wave >> 2, wn = wave & 3;

  f32x4 acc[4][2] = {};

  const unsigned short* gA = A + (size_t)(m0 + (t >> 2)) * K + (t & 3) * 8;
  const unsigned short* gB = Bt + (size_t)(n0 + (t >> 2)) * K + (t & 3) * 8;

#define GSTAGE(buf_, k_)                                                  \
  do {                                                                    \
    glds16(gA + (k_), (char*)As[buf_] + t * 16);                          \
    glds16(gB + (k_), (char*)Bs[buf_] + t * 16);                          \
  } while (0)

  const int nst = K >> 5;
  GSTAGE(0, 0);
  GSTAGE(1, 32);

  for (int st = 0; st < nst; ++st) {
    __builtin_amdgcn_s_barrier();          // A: guards slot (st+2)%3 overwrite
    __builtin_amdgcn_sched_barrier(0);
    if (st + 2 < nst) GSTAGE((st + 2) % 3, (st + 2) * 32);
    __builtin_amdgcn_sched_barrier(0);
    if (st + 2 < nst)      asm volatile("s_waitcnt vmcnt(4)" ::: "memory");
    else if (st + 1 < nst) asm volatile("s_waitcnt vmcnt(2)" ::: "memory");
    else                   asm volatile("s_waitcnt vmcnt(0)" ::: "memory");
    __builtin_amdgcn_s_barrier();          // B: all waves' stage(st) visible
    __builtin_amdgcn_sched_barrier(0);

    const unsigned short* Ab = As[st % 3];
    const unsigned short* Bb = Bs[st % 3];
    bf16x8 av[4], bv[2];
#pragma unroll
    for (int i = 0; i < 4; i++)
      av[i] = ld8(Ab + (wm * 64 + i * 16 + lr) * 32 + lg * 8);
#pragma unroll
    for (int j = 0; j < 2; j++)
      bv[j] = ld8(Bb + (wn * 32 + j * 16 + lr) * 32 + lg * 8);
    __builtin_amdgcn_s_setprio(1);
#pragma unroll
    for (int i = 0; i < 4; i++)
#pragma unroll
      for (int j = 0; j < 2; j++)
        acc[i][j] = mfma16(av[i], bv[j], acc[i][j]);
    __builtin_amdgcn_s_setprio(0);
  }
#undef GSTAGE

  if (OUT_BF16 && vtOut != nullptr && n0 >= 2 * CC) {
    // V third: write vt[bh][d][t] directly (b=row>>11, t=row&2047)
#pragma unroll
    for (int j2 = 0; j2 < 2; j2++) {
      int cv = n0 - 2 * CC + wn * 32 + j2 * 16 + lr;  // h*64 + d
      int h = cv >> 6, d = cv & 63;
      float bv_ = bias[2 * CC + cv];
#pragma unroll
      for (int i = 0; i < 4; i++) {
        int row = m0 + wm * 64 + i * 16 + lg * 4;
        int bb = row >> 11, t2 = row & 2047;
        ushort4 wv;
        wv.x = f2bf(acc[i][j2][0] + bv_);
        wv.y = f2bf(acc[i][j2][1] + bv_);
        wv.z = f2bf(acc[i][j2][2] + bv_);
        wv.w = f2bf(acc[i][j2][3] + bv_);
        *(ushort4*)(vtOut + (((size_t)(bb * NHH + h) * HSS + d) << 11) + t2) = wv;
      }
    }
    return;
  }

#pragma unroll
  for (int j2 = 0; j2 < 2; j2++) {
    int col = n0 + wn * 32 + j2 * 16 + lr;
    float bv_ = bias[col];
#pragma unroll
    for (int i = 0; i < 4; i++) {
      int row = m0 + wm * 64 + i * 16 + lg * 4;
#pragma unroll
      for (int r = 0; r < 4; r++) {
        float v = acc[i][j2][r] + bv_;
        if (OUT_BF16)
          ((unsigned short*)Cout)[(size_t)(row + r) * N + col] = f2bf(v);
        else
          ((float*)Cout)[(size_t)(row + r) * N + col] = v;
      }
    }
  }
}

// ---------- flash attention: 8 waves, kv-parity split, paired q-tiles ----------
// (round-9 structure, proven 42us; this round: depth-6 TREE reductions replace
// the 32-deep serial fmax/fadd chains in the per-step softmax)
__global__ __launch_bounds__(512) void k_attn(const unsigned short* __restrict__ qkv,
                                              const unsigned short* __restrict__ vt,
                                              unsigned short* __restrict__ y) {
  __shared__ __align__(16) unsigned short Ks[3][128 * 64];
  __shared__ __align__(16) unsigned short Vs[3][128 * 64];
  __shared__ __align__(16) unsigned short Ps[8][32 * 64];
  __shared__ float Msh[4][64];
  __shared__ float Lsh[4][64];
  const int t = threadIdx.x;
  const int w = t >> 6, l = t & 63, lq = l & 31, hl = l >> 5;
  const int qsub = w & 3, par = w >> 2;
  const int id = blockIdx.x;
  const int bh = (id & 7) + 8 * ((id >> 3) & 3);
  const int p = id >> 5;  // 0..7
  const int b = bh >> 4, head = bh & 15;
  const int jA = 15 - p, jB = p;
  const int mA = jA + 1;        // + (jB+1) = 17 macro-steps
  const int NT = 17;
  const float cexp = 0.18033688011112042f;  // (1/8)*log2(e)
  const float THR = 40.0f;

#define SWZ(r_) ((((r_) & 7) ^ (((r_) >> 3) & 3)) << 4)

  const int myswz = SWZ(lq);
  int offs[4];
#pragma unroll
  for (int s = 0; s < 4; s++) offs[s] = (32 * s + 16 * hl) ^ myswz;

  // staging: two glds16 issues per array; linear LDS off = i*8192 + w*1024 + l*16
  const int off0 = w * 1024 + l * 16;
  const int off1 = 8192 + w * 1024 + l * 16;
  const int rk0 = off0 >> 7, rk1 = off1 >> 7;          // K rows 0..127
  const int ck0 = (off0 & 127) ^ SWZ(rk0), ck1 = (off1 & 127) ^ SWZ(rk1);
  const int rv0 = rk0 & 63, rv1 = rk1 & 63;            // V rows 0..63, subtile = i
  const int cv0 = (off0 & 127) ^ SWZ(rv0), cv1 = (off1 & 127) ^ SWZ(rv1);
  const char* gK0 = (const char*)(qkv + (size_t)(b * TT + rk0) * N3 + CC + head * HSS) + ck0;
  const char* gK1 = (const char*)(qkv + (size_t)(b * TT + rk1) * N3 + CC + head * HSS) + ck1;
  const char* gV0 = (const char*)(vt + ((size_t)bh * HSS + rv0) * TT) + cv0;        // kv 0..63
  const char* gV1 = (const char*)(vt + ((size_t)bh * HSS + rv1) * TT + 64) + cv1;   // kv 64..127
  const int dK0 = w * 1024, dK1 = 8192 + w * 1024;

#define STAGE(slot_, kvt_)                                                \
  do {                                                                    \
    size_t kb = (size_t)(kvt_) * (128 * N3 * 2);                          \
    size_t vb = (size_t)(kvt_) * 256;                                     \
    glds16(gK0 + kb, (char*)Ks[slot_] + dK0);                             \
    glds16(gK1 + kb, (char*)Ks[slot_] + dK1);                             \
    glds16(gV0 + vb, (char*)Vs[slot_] + dK0);                             \
    glds16(gV1 + vb, (char*)Vs[slot_] + dK1);                             \
  } while (0)

#define WRITE_OUT()                                                       \
  do {                                                                    \
    float l_q = l_ln + __shfl_xor(l_ln, 32);                              \
    float inv = 1.0f / l_q;                                               \
    unsigned short* ybase = y + (size_t)(b * TT + q0w + lq) * CC + head * HSS; \
    _Pragma("unroll")                                                     \
    for (int g = 0; g < 4; g++) {                                         \
      ushort4 wv;                                                         \
      wv.x = f2bf(oa[4 * g + 0] * inv); wv.y = f2bf(oa[4 * g + 1] * inv); \
      wv.z = f2bf(oa[4 * g + 2] * inv); wv.w = f2bf(oa[4 * g + 3] * inv); \
      *(ushort4*)(ybase + 8 * g + 4 * hl) = wv;                           \
      ushort4 wv2;                                                        \
      wv2.x = f2bf(ob[4 * g + 0] * inv); wv2.y = f2bf(ob[4 * g + 1] * inv); \
      wv2.z = f2bf(ob[4 * g + 2] * inv); wv2.w = f2bf(ob[4 * g + 3] * inv); \
      *(ushort4*)(ybase + 32 + 8 * g + 4 * hl) = wv2;                     \
    }                                                                     \
  } while (0)

// cross-parity merge: par1 writes (oa,ob,m,l) through Ps; par0 combines + stores y
#define MERGE()                                                           \
  do {                                                                    \
    __builtin_amdgcn_s_barrier();                                         \
    if (par) {                                                            \
      float* poa = (float*)Ps[w];                                         \
      float* pob = (float*)Ps[w - 4];                                     \
      _Pragma("unroll")                                                   \
      for (int g = 0; g < 16; g++) { poa[g * 64 + l] = oa[g]; pob[g * 64 + l] = ob[g]; } \
      Msh[qsub][l] = m_s; Lsh[qsub][l] = l_ln;                            \
    }                                                                     \
    asm volatile("s_waitcnt lgkmcnt(0)" ::: "memory");                    \
    __builtin_amdgcn_s_barrier();                                         \
    __builtin_amdgcn_sched_barrier(0);                                    \
    if (!par) {                                                           \
      float m1 = Msh[qsub][l], l1 = Lsh[qsub][l];                         \
      float mstar = fmaxf(m_s, m1);                                       \
      float a0 = __builtin_amdgcn_exp2f((m_s - mstar) * cexp);            \
      float a1 = __builtin_amdgcn_exp2f((m1 - mstar) * cexp);             \
      const float* poa = (const float*)Ps[w + 4];                         \
      const float* pob = (const float*)Ps[w];                             \
      _Pragma("unroll")                                                   \
      for (int g = 0; g < 16; g++) {                                      \
        oa[g] = oa[g] * a0 + poa[g * 64 + l] * a1;                        \
        ob[g] = ob[g] * a0 + pob[g * 64 + l] * a1;                        \
      }                                                                   \
      l_ln = l_ln * a0 + l1 * a1;                                         \
      WRITE_OUT();                                                        \
    }                                                                     \
    __builtin_amdgcn_s_barrier();                                         \
  } while (0)

  // segment A state
  int q0w = jA * 128 + qsub * 32;
  const unsigned short* qp = qkv + (size_t)(b * TT + q0w + lq) * N3 + head * HSS + hl * 8;
  bf16x8 qf0 = ld8(qp), qf1 = ld8(qp + 16), qf2 = ld8(qp + 32), qf3 = ld8(qp + 48);
  float m_s = -INFINITY, l_ln = 0.f;
  f32x16 oa = z16(), ob = z16();
  char* prow = (char*)Ps[w] + lq * 128;

  STAGE(0, 0);
  int cur = 0;

  for (int seq = 0; seq < NT; ++seq) {
    if (seq == mA) {
      MERGE();  // finalize segment A; y written by par0
      q0w = jB * 128 + qsub * 32;
      const unsigned short* qp2 = qkv + (size_t)(b * TT + q0w + lq) * N3 + head * HSS + hl * 8;
      qf0 = ld8(qp2); qf1 = ld8(qp2 + 16); qf2 = ld8(qp2 + 32); qf3 = ld8(qp2 + 48);
      m_s = -INFINITY; l_ln = 0.f;
      oa = z16(); ob = z16();
    }

    const int kvt = (seq < mA) ? seq : (seq - mA);
    if (seq + 1 < NT) {
      int s2 = seq + 1;
      int kvt2 = (s2 < mA) ? s2 : (s2 - mA);
      int nxt = (cur == 2) ? 0 : cur + 1;
      STAGE(nxt, kvt2);
      __builtin_amdgcn_sched_barrier(0);
      asm volatile("s_waitcnt vmcnt(4)" ::: "memory");
    } else {
      asm volatile("s_waitcnt vmcnt(0)" ::: "memory");
    }
    __builtin_amdgcn_s_barrier();
    __builtin_amdgcn_sched_barrier(0);

    const int mybuf = cur;
    cur = (cur == 2) ? 0 : cur + 1;

    const int kv0w = kvt * 128 + 64 * par;
    if (kv0w > q0w + 31) continue;  // fully-masked for this wave (barriers done)

    const unsigned short* Kb = Ks[mybuf];
    const unsigned short* Vb = Vs[mybuf];

    // QK^T swapped: sa/sb hold S^T[kv][q=lq], kv=kv0w+(g&3)+8*(g>>2)+4*hl (+32 sb)
    const char* krA = (const char*)Kb + (64 * par + lq) * 128;
    const char* krB = krA + 32 * 128;
    f32x16 sa = z16(), sb = z16();
    __builtin_amdgcn_s_setprio(1);
    {
      bf16x8 ka, kb8;
      ka = ld8((const unsigned short*)(krA + offs[0]));
      kb8 = ld8((const unsigned short*)(krB + offs[0]));
      sa = mfma32(ka, qf0, sa); sb = mfma32(kb8, qf0, sb);
      ka = ld8((const unsigned short*)(krA + offs[1]));
      kb8 = ld8((const unsigned short*)(krB + offs[1]));
      sa = mfma32(ka, qf1, sa); sb = mfma32(kb8, qf1, sb);
      ka = ld8((const unsigned short*)(krA + offs[2]));
      kb8 = ld8((const unsigned short*)(krB + offs[2]));
      sa = mfma32(ka, qf2, sa); sb = mfma32(kb8, qf2, sb);
      ka = ld8((const unsigned short*)(krA + offs[3]));
      kb8 = ld8((const unsigned short*)(krB + offs[3]));
      sa = mfma32(ka, qf3, sa); sb = mfma32(kb8, qf3, sb);
    }
    __builtin_amdgcn_s_setprio(0);

    // causal mask near the diagonal
    if (kv0w + 63 > q0w) {
      const int q = q0w + lq;
#pragma unroll
      for (int g = 0; g < 16; g++) {
        int kvl = kv0w + (g & 3) + 8 * (g >> 2) + 4 * hl;
        if (kvl > q) sa[g] = -INFINITY;
        if (kvl + 32 > q) sb[g] = -INFINITY;
      }
    }

    // per-lane max: depth-6 tree, then cross-half combine
    float m8t[8];
#pragma unroll
    for (int g = 0; g < 8; g++)
      m8t[g] = fmaxf(fmaxf(sa[g], sa[g + 8]), fmaxf(sb[g], sb[g + 8]));
    float m4a = fmaxf(fmaxf(m8t[0], m8t[1]), fmaxf(m8t[2], m8t[3]));
    float m4b = fmaxf(fmaxf(m8t[4], m8t[5]), fmaxf(m8t[6], m8t[7]));
    float tmax = fmaxf(m4a, m4b);
    tmax = fmaxf(tmax, __shfl_xor(tmax, 32));

    if (!__all(tmax <= m_s + THR)) {
      float m_new = fmaxf(m_s, tmax);
      float alpha = __builtin_amdgcn_exp2f((m_s - m_new) * cexp);
      l_ln *= alpha;
#pragma unroll
      for (int g = 0; g < 16; g++) { oa[g] *= alpha; ob[g] *= alpha; }
      m_s = m_new;
    }

    // exp in place; tree-sum into l (depth-6 instead of 32-deep serial adds)
    const float mc = m_s * cexp;
#pragma unroll
    for (int g = 0; g < 16; g++) {
      sa[g] = __builtin_amdgcn_exp2f(__builtin_fmaf(sa[g], cexp, -mc));
      sb[g] = __builtin_amdgcn_exp2f(__builtin_fmaf(sb[g], cexp, -mc));
    }
    {
      float s8t[8];
#pragma unroll
      for (int g = 0; g < 8; g++)
        s8t[g] = (sa[g] + sa[g + 8]) + (sb[g] + sb[g + 8]);
      float s4a = (s8t[0] + s8t[1]) + (s8t[2] + s8t[3]);
      float s4b = (s8t[4] + s8t[5]) + (s8t[6] + s8t[7]);
      l_ln += s4a + s4b;
    }

    // P -> LDS bounce (wave-private)
#pragma unroll
    for (int u2 = 0; u2 < 4; u2++) {
      bf16x4 w0, w1;
#pragma unroll
      for (int r = 0; r < 4; r++) { w0[r] = (__bf16)sa[4 * u2 + r]; w1[r] = (__bf16)sb[4 * u2 + r]; }
      *(bf16x4*)(prow + ((16 * u2 + 8 * hl) ^ myswz)) = w0;
      *(bf16x4*)(prow + ((64 + 16 * u2 + 8 * hl) ^ myswz)) = w1;
    }
    asm volatile("s_waitcnt lgkmcnt(0)" ::: "memory");
    __builtin_amdgcn_sched_barrier(0);
    bf16x8 pf0 = ld8((const unsigned short*)(prow + offs[0]));
    bf16x8 pf1 = ld8((const unsigned short*)(prow + offs[1]));
    bf16x8 pf2 = ld8((const unsigned short*)(prow + offs[2]));
    bf16x8 pf3 = ld8((const unsigned short*)(prow + offs[3]));

    // PV on this wave's V subtile (kv parity half)
    const char* vrA = (const char*)Vb + par * 8192 + lq * 128;
    const char* vrB = vrA + 32 * 128;
    __builtin_amdgcn_s_setprio(1);
    {
      bf16x8 va, vb8;
      va = ld8((const unsigned short*)(vrA + offs[0]));
      vb8 = ld8((const unsigned short*)(vrB + offs[0]));
      oa = mfma32(va, pf0, oa); ob = mfma32(vb8, pf0, ob);
      va = ld8((const unsigned short*)(vrA + offs[1]));
      vb8 = ld8((const unsigned short*)(vrB + offs[1]));
      oa = mfma32(va, pf1, oa); ob = mfma32(vb8, pf1, ob);
      va = ld8((const unsigned short*)(vrA + offs[2]));
      vb8 = ld8((const unsigned short*)(vrB + offs[2]));
      oa = mfma32(va, pf2, oa); ob = mfma32(vb8, pf2, ob);
      va = ld8((const unsigned short*)(vrA + offs[3]));
      vb8 = ld8((const unsigned short*)(vrB + offs[3]));
      oa = mfma32(va, pf3, oa); ob = mfma32(vb8, pf3, ob);
    }
    __builtin_amdgcn_s_setprio(0);
  }

  MERGE();  // finalize segment B
#undef STAGE
#undef WRITE_OUT
#undef MERGE
#undef SWZ
}

extern "C" void kernel_launch(void* const* d_in, const int* in_sizes, int n_in,
                              void* d_out, int out_size, void* d_ws, size_t ws_size,
                              hipStream_t stream) {
  const float* x = (const float*)d_in[0];
  const float* W_attn = (const float*)d_in[1];
  const float* b_attn = (const float*)d_in[2];
  const float* W_proj = (const float*)d_in[3];
  const float* b_proj = (const float*)d_in[4];

  char* ws = (char*)d_ws;
  unsigned short* xb   = (unsigned short*)(ws);                       // 8 MB
  unsigned short* wabt = (unsigned short*)(ws + 8388608);             // 6 MB  [3072][1024]
  unsigned short* wpbt = (unsigned short*)(ws + 14680064);            // 2 MB  [1024][1024]
  unsigned short* qkvb = (unsigned short*)(ws + 16777216);            // 24 MB [4096][3072]
  unsigned short* vt   = (unsigned short*)(ws + 41943040);            // 8 MB  [32][64][2048]
  unsigned short* yb   = (unsigned short*)(ws + 50331648);            // 8 MB  [4096][1024]

  k_prep<<<dim3(5120), 256, 0, stream>>>(x, W_attn, W_proj, xb, wabt, wpbt);
  // QKV: M=4096, N=3072 -> 32x24 tiles = 768 blocks; XCD grid 4x2, region 8Mx12N
  // V third written transposed to vt directly (k_vt fused into epilogue).
  k_gemm<1><<<dim3(768), 512, 0, stream>>>(xb, wabt, b_attn, qkvb, vt, N3, CC, 8, 12, 2);
  k_attn<<<dim3(256), 512, 0, stream>>>(qkvb, vt, yb);
  // proj: M=4096, N=1024 -> 32x8 tiles = 256 blocks; XCD grid 8x1, region 4Mx8N
  k_gemm<0><<<dim3(256), 512, 0, stream>>>(yb, wpbt, b_proj, d_out, nullptr, CC, CC, 4, 8, 1);
}

// Round 20
// 102.506 us; speedup vs baseline: 1.2511x; 1.0311x over previous
//
#include <hip/hip_runtime.h>
#include <hip/hip_bf16.h>
#include <stdint.h>

#define DEV static __device__ __forceinline__

typedef __attribute__((ext_vector_type(8))) __bf16 bf16x8;
typedef __attribute__((ext_vector_type(4))) __bf16 bf16x4;
typedef __attribute__((ext_vector_type(4))) float f32x4;
typedef __attribute__((ext_vector_type(16))) float f32x16;

// B=2, T=2048, C=1024, NH=16, HS=64
#define BB 2
#define TT 2048
#define CC 1024
#define NHH 16
#define HSS 64
#define BT 4096
#define N3 3072

DEV unsigned short f2bf(float f) {
  union { float f; uint32_t u; } v; v.f = f;
  uint32_t r = v.u + 0x7FFFu + ((v.u >> 16) & 1u);
  return (unsigned short)(r >> 16);
}

typedef const __attribute__((address_space(1))) unsigned int* gas_t;
typedef __attribute__((address_space(3))) unsigned int* las_t;

DEV void glds16(const void* g, void* l) {
  __builtin_amdgcn_global_load_lds((gas_t)g, (las_t)l, 16, 0, 0);
}

DEV f32x4 mfma16(bf16x8 a, bf16x8 b, f32x4 c) {
  return __builtin_amdgcn_mfma_f32_16x16x32_bf16(a, b, c, 0, 0, 0);
}
DEV f32x16 mfma32(bf16x8 a, bf16x8 b, f32x16 c) {
  return __builtin_amdgcn_mfma_f32_32x32x16_bf16(a, b, c, 0, 0, 0);
}

DEV bf16x8 ld8(const unsigned short* p) { return *(const bf16x8*)p; }

DEV f32x16 z16() {
  f32x16 v;
#pragma unroll
  for (int i = 0; i < 16; i++) v[i] = 0.f;
  return v;
}

// ---------- fused prep: x conv (blocks 0..1023) + W_attn transp (1024..4095)
// + W_proj transp (4096..5119). 256 threads/block.
__global__ __launch_bounds__(256) void k_prep(const float* __restrict__ x,
                                              const float* __restrict__ Wa,
                                              const float* __restrict__ Wp,
                                              unsigned short* __restrict__ xb,
                                              unsigned short* __restrict__ wabt,
                                              unsigned short* __restrict__ wpbt) {
  const int bid = blockIdx.x;
  const int t = threadIdx.x;
  if (bid < 1024) {
    int i = bid * 256 + t;
    const int n4 = BT * CC / 4;
#pragma unroll
    for (int r = 0; r < 4; r++, i += 262144) {
      if (i < n4) {
        float4 v = ((const float4*)x)[i];
        ushort4 o;
        o.x = f2bf(v.x); o.y = f2bf(v.y); o.z = f2bf(v.z); o.w = f2bf(v.w);
        ((ushort4*)xb)[i] = o;
      }
    }
    return;
  }
  __shared__ float tile[32][33];
  const float* in;
  unsigned short* out;
  int N, tid;
  if (bid < 4096) { in = Wa; out = wabt; N = N3; tid = bid - 1024; }
  else            { in = Wp; out = wpbt; N = CC; tid = bid - 4096; }
  const int ntx = N / 32;
  const int n0 = (tid % ntx) * 32, k0 = (tid / ntx) * 32;
  const int tx = t & 31, ty = t >> 5;
  for (int r = ty; r < 32; r += 8)
    tile[r][tx] = in[(size_t)(k0 + r) * N + n0 + tx];
  __syncthreads();
  for (int r = ty; r < 32; r += 8)
    out[(size_t)(n0 + r) * CC + k0 + tx] = f2bf(tile[tx][r]);
}

// ---------- GEMM: A[M][K] bf16, Bt[N][K] bf16, bias f32[N] ----------
// 128x128 tile, BK=32, 8 waves (2M x 4N, 64x32 per wave), ring-3 LDS (48KB),
// depth-2 prefetch + counted vmcnt. XCD-region decode. When vtOut != nullptr
// and the tile is in the V third (n0 >= 2048), the epilogue writes the
// per-head transposed V layout vt[bh][d][t] directly (replaces k_vt).
template <int OUT_BF16>
__global__ __launch_bounds__(512) void k_gemm(const unsigned short* __restrict__ A,
                                              const unsigned short* __restrict__ Bt,
                                              const float* __restrict__ bias,
                                              void* __restrict__ Cout,
                                              unsigned short* __restrict__ vtOut,
                                              int N, int K, int Rm, int Rn, int Xn) {
  __shared__ __align__(16) unsigned short As[3][128 * 32];
  __shared__ __align__(16) unsigned short Bs[3][128 * 32];
  const int t = threadIdx.x;
  const int wave = t >> 6, l = t & 63, lr = l & 15, lg = l >> 4;
  const int xcd = (int)blockIdx.x & 7, q = (int)blockIdx.x >> 3;
  const int m0 = ((xcd / Xn) * Rm + (q % Rm)) * 128;
  const int n0 = ((xcd % Xn) * Rn + (q / Rm)) * 128;
  const int wm = wave >> 2, wn = wave & 3;

  f32x4 acc[4][2] = {};

  const unsigned short* gA = A + (size_t)(m0 + (t >> 2)) * K + (t & 3) * 8;
  const unsigned short* gB = Bt + (size_t)(n0 + (t >> 2)) * K + (t & 3) * 8;

#define GSTAGE(buf_, k_)                                                  \
  do {                                                                    \
    glds16(gA + (k_), (char*)As[buf_] + t * 16);                          \
    glds16(gB + (k_), (char*)Bs[buf_] + t * 16);                          \
  } while (0)

  const int nst = K >> 5;
  GSTAGE(0, 0);
  GSTAGE(1, 32);

  for (int st = 0; st < nst; ++st) {
    __builtin_amdgcn_s_barrier();          // A: guards slot (st+2)%3 overwrite
    __builtin_amdgcn_sched_barrier(0);
    if (st + 2 < nst) GSTAGE((st + 2) % 3, (st + 2) * 32);
    __builtin_amdgcn_sched_barrier(0);
    if (st + 2 < nst)      asm volatile("s_waitcnt vmcnt(4)" ::: "memory");
    else if (st + 1 < nst) asm volatile("s_waitcnt vmcnt(2)" ::: "memory");
    else                   asm volatile("s_waitcnt vmcnt(0)" ::: "memory");
    __builtin_amdgcn_s_barrier();          // B: all waves' stage(st) visible
    __builtin_amdgcn_sched_barrier(0);

    const unsigned short* Ab = As[st % 3];
    const unsigned short* Bb = Bs[st % 3];
    bf16x8 av[4], bv[2];
#pragma unroll
    for (int i = 0; i < 4; i++)
      av[i] = ld8(Ab + (wm * 64 + i * 16 + lr) * 32 + lg * 8);
#pragma unroll
    for (int j = 0; j < 2; j++)
      bv[j] = ld8(Bb + (wn * 32 + j * 16 + lr) * 32 + lg * 8);
    __builtin_amdgcn_s_setprio(1);
#pragma unroll
    for (int i = 0; i < 4; i++)
#pragma unroll
      for (int j = 0; j < 2; j++)
        acc[i][j] = mfma16(av[i], bv[j], acc[i][j]);
    __builtin_amdgcn_s_setprio(0);
  }
#undef GSTAGE

  if (OUT_BF16 && vtOut != nullptr && n0 >= 2 * CC) {
    // V third: write vt[bh][d][t] directly (b=row>>11, t=row&2047)
#pragma unroll
    for (int j2 = 0; j2 < 2; j2++) {
      int cv = n0 - 2 * CC + wn * 32 + j2 * 16 + lr;  // h*64 + d
      int h = cv >> 6, d = cv & 63;
      float bv_ = bias[2 * CC + cv];
#pragma unroll
      for (int i = 0; i < 4; i++) {
        int row = m0 + wm * 64 + i * 16 + lg * 4;
        int bb = row >> 11, t2 = row & 2047;
        ushort4 wv;
        wv.x = f2bf(acc[i][j2][0] + bv_);
        wv.y = f2bf(acc[i][j2][1] + bv_);
        wv.z = f2bf(acc[i][j2][2] + bv_);
        wv.w = f2bf(acc[i][j2][3] + bv_);
        *(ushort4*)(vtOut + (((size_t)(bb * NHH + h) * HSS + d) << 11) + t2) = wv;
      }
    }
    return;
  }

#pragma unroll
  for (int j2 = 0; j2 < 2; j2++) {
    int col = n0 + wn * 32 + j2 * 16 + lr;
    float bv_ = bias[col];
#pragma unroll
    for (int i = 0; i < 4; i++) {
      int row = m0 + wm * 64 + i * 16 + lg * 4;
#pragma unroll
      for (int r = 0; r < 4; r++) {
        float v = acc[i][j2][r] + bv_;
        if (OUT_BF16)
          ((unsigned short*)Cout)[(size_t)(row + r) * N + col] = f2bf(v);
        else
          ((float*)Cout)[(size_t)(row + r) * N + col] = v;
      }
    }
  }
}

// ---------- proj GEMM: 128x64 tile, 4 waves (2Mx2N), 256 thr, ring-3 ----------
// 512 blocks -> 4 blocks/CU (36KB LDS), 4 waves/SIMD. Same proven schedule:
// depth-2 prefetch, counted vmcnt (3 issues/stage -> 6/3/0), 2 barriers/step.
// XCD decode: grid 4x2, region 8M x 8N tiles.
__global__ __launch_bounds__(256) void k_gemmp(const unsigned short* __restrict__ A,
                                               const unsigned short* __restrict__ Bt,
                                               const float* __restrict__ bias,
                                               float* __restrict__ Cout) {
  __shared__ __align__(16) unsigned short As[3][128 * 32];
  __shared__ __align__(16) unsigned short Bs[3][64 * 32];
  const int t = threadIdx.x;
  const int wave = t >> 6, l = t & 63, lr = l & 15, lg = l >> 4;
  const int xcd = (int)blockIdx.x & 7, q = (int)blockIdx.x >> 3;  // q 0..63
  const int m0 = ((xcd >> 1) * 8 + (q & 7)) * 128;
  const int n0 = ((xcd & 1) * 8 + (q >> 3)) * 64;
  const int wm = wave >> 1, wn = wave & 1;
  const int K = CC, N = CC;

  f32x4 acc[4][2] = {};

  // staging: thread t -> row t>>2, 16B chunk (t&3). A: 2 issues (rows 0-63,
  // 64-127). B: 1 issue (rows 0-63).
  const unsigned short* gA = A + (size_t)(m0 + (t >> 2)) * K + (t & 3) * 8;
  const unsigned short* gB = Bt + (size_t)(n0 + (t >> 2)) * K + (t & 3) * 8;
  const size_t arst = (size_t)64 * K;

#define GSTAGEP(buf_, k_)                                                 \
  do {                                                                    \
    glds16(gA + (k_), (char*)As[buf_] + t * 16);                          \
    glds16(gA + arst + (k_), (char*)As[buf_] + 4096 + t * 16);            \
    glds16(gB + (k_), (char*)Bs[buf_] + t * 16);                          \
  } while (0)

  const int nst = K >> 5;  // 32
  GSTAGEP(0, 0);
  GSTAGEP(1, 32);

  for (int st = 0; st < nst; ++st) {
    __builtin_amdgcn_s_barrier();          // A: guards slot (st+2)%3 overwrite
    __builtin_amdgcn_sched_barrier(0);
    if (st + 2 < nst) GSTAGEP((st + 2) % 3, (st + 2) * 32);
    __builtin_amdgcn_sched_barrier(0);
    if (st + 2 < nst)      asm volatile("s_waitcnt vmcnt(6)" ::: "memory");
    else if (st + 1 < nst) asm volatile("s_waitcnt vmcnt(3)" ::: "memory");
    else                   asm volatile("s_waitcnt vmcnt(0)" ::: "memory");
    __builtin_amdgcn_s_barrier();          // B: all waves' stage(st) visible
    __builtin_amdgcn_sched_barrier(0);

    const unsigned short* Ab = As[st % 3];
    const unsigned short* Bb = Bs[st % 3];
    bf16x8 av[4], bv[2];
#pragma unroll
    for (int i = 0; i < 4; i++)
      av[i] = ld8(Ab + (wm * 64 + i * 16 + lr) * 32 + lg * 8);
#pragma unroll
    for (int j = 0; j < 2; j++)
      bv[j] = ld8(Bb + (wn * 32 + j * 16 + lr) * 32 + lg * 8);
    __builtin_amdgcn_s_setprio(1);
#pragma unroll
    for (int i = 0; i < 4; i++)
#pragma unroll
      for (int j = 0; j < 2; j++)
        acc[i][j] = mfma16(av[i], bv[j], acc[i][j]);
    __builtin_amdgcn_s_setprio(0);
  }
#undef GSTAGEP

#pragma unroll
  for (int j2 = 0; j2 < 2; j2++) {
    int col = n0 + wn * 32 + j2 * 16 + lr;
    float bv_ = bias[col];
#pragma unroll
    for (int i = 0; i < 4; i++) {
      int row = m0 + wm * 64 + i * 16 + lg * 4;
#pragma unroll
      for (int r = 0; r < 4; r++)
        Cout[(size_t)(row + r) * N + col] = acc[i][j2][r] + bv_;
    }
  }
}

// ---------- flash attention: 8 waves, kv-parity split, paired q-tiles ----------
// (round-9 structure + depth-6 tree reductions; proven 41.5us)
__global__ __launch_bounds__(512) void k_attn(const unsigned short* __restrict__ qkv,
                                              const unsigned short* __restrict__ vt,
                                              unsigned short* __restrict__ y) {
  __shared__ __align__(16) unsigned short Ks[3][128 * 64];
  __shared__ __align__(16) unsigned short Vs[3][128 * 64];
  __shared__ __align__(16) unsigned short Ps[8][32 * 64];
  __shared__ float Msh[4][64];
  __shared__ float Lsh[4][64];
  const int t = threadIdx.x;
  const int w = t >> 6, l = t & 63, lq = l & 31, hl = l >> 5;
  const int qsub = w & 3, par = w >> 2;
  const int id = blockIdx.x;
  const int bh = (id & 7) + 8 * ((id >> 3) & 3);
  const int p = id >> 5;  // 0..7
  const int b = bh >> 4, head = bh & 15;
  const int jA = 15 - p, jB = p;
  const int mA = jA + 1;        // + (jB+1) = 17 macro-steps
  const int NT = 17;
  const float cexp = 0.18033688011112042f;  // (1/8)*log2(e)
  const float THR = 40.0f;

#define SWZ(r_) ((((r_) & 7) ^ (((r_) >> 3) & 3)) << 4)

  const int myswz = SWZ(lq);
  int offs[4];
#pragma unroll
  for (int s = 0; s < 4; s++) offs[s] = (32 * s + 16 * hl) ^ myswz;

  // staging: two glds16 issues per array; linear LDS off = i*8192 + w*1024 + l*16
  const int off0 = w * 1024 + l * 16;
  const int off1 = 8192 + w * 1024 + l * 16;
  const int rk0 = off0 >> 7, rk1 = off1 >> 7;          // K rows 0..127
  const int ck0 = (off0 & 127) ^ SWZ(rk0), ck1 = (off1 & 127) ^ SWZ(rk1);
  const int rv0 = rk0 & 63, rv1 = rk1 & 63;            // V rows 0..63, subtile = i
  const int cv0 = (off0 & 127) ^ SWZ(rv0), cv1 = (off1 & 127) ^ SWZ(rv1);
  const char* gK0 = (const char*)(qkv + (size_t)(b * TT + rk0) * N3 + CC + head * HSS) + ck0;
  const char* gK1 = (const char*)(qkv + (size_t)(b * TT + rk1) * N3 + CC + head * HSS) + ck1;
  const char* gV0 = (const char*)(vt + ((size_t)bh * HSS + rv0) * TT) + cv0;        // kv 0..63
  const char* gV1 = (const char*)(vt + ((size_t)bh * HSS + rv1) * TT + 64) + cv1;   // kv 64..127
  const int dK0 = w * 1024, dK1 = 8192 + w * 1024;

#define STAGE(slot_, kvt_)                                                \
  do {                                                                    \
    size_t kb = (size_t)(kvt_) * (128 * N3 * 2);                          \
    size_t vb = (size_t)(kvt_) * 256;                                     \
    glds16(gK0 + kb, (char*)Ks[slot_] + dK0);                             \
    glds16(gK1 + kb, (char*)Ks[slot_] + dK1);                             \
    glds16(gV0 + vb, (char*)Vs[slot_] + dK0);                             \
    glds16(gV1 + vb, (char*)Vs[slot_] + dK1);                             \
  } while (0)

#define WRITE_OUT()                                                       \
  do {                                                                    \
    float l_q = l_ln + __shfl_xor(l_ln, 32);                              \
    float inv = 1.0f / l_q;                                               \
    unsigned short* ybase = y + (size_t)(b * TT + q0w + lq) * CC + head * HSS; \
    _Pragma("unroll")                                                     \
    for (int g = 0; g < 4; g++) {                                         \
      ushort4 wv;                                                         \
      wv.x = f2bf(oa[4 * g + 0] * inv); wv.y = f2bf(oa[4 * g + 1] * inv); \
      wv.z = f2bf(oa[4 * g + 2] * inv); wv.w = f2bf(oa[4 * g + 3] * inv); \
      *(ushort4*)(ybase + 8 * g + 4 * hl) = wv;                           \
      ushort4 wv2;                                                        \
      wv2.x = f2bf(ob[4 * g + 0] * inv); wv2.y = f2bf(ob[4 * g + 1] * inv); \
      wv2.z = f2bf(ob[4 * g + 2] * inv); wv2.w = f2bf(ob[4 * g + 3] * inv); \
      *(ushort4*)(ybase + 32 + 8 * g + 4 * hl) = wv2;                     \
    }                                                                     \
  } while (0)

// cross-parity merge: par1 writes (oa,ob,m,l) through Ps; par0 combines + stores y
#define MERGE()                                                           \
  do {                                                                    \
    __builtin_amdgcn_s_barrier();                                         \
    if (par) {                                                            \
      float* poa = (float*)Ps[w];                                         \
      float* pob = (float*)Ps[w - 4];                                     \
      _Pragma("unroll")                                                   \
      for (int g = 0; g < 16; g++) { poa[g * 64 + l] = oa[g]; pob[g * 64 + l] = ob[g]; } \
      Msh[qsub][l] = m_s; Lsh[qsub][l] = l_ln;                            \
    }                                                                     \
    asm volatile("s_waitcnt lgkmcnt(0)" ::: "memory");                    \
    __builtin_amdgcn_s_barrier();                                         \
    __builtin_amdgcn_sched_barrier(0);                                    \
    if (!par) {                                                           \
      float m1 = Msh[qsub][l], l1 = Lsh[qsub][l];                         \
      float mstar = fmaxf(m_s, m1);                                       \
      float a0 = __builtin_amdgcn_exp2f((m_s - mstar) * cexp);            \
      float a1 = __builtin_amdgcn_exp2f((m1 - mstar) * cexp);             \
      const float* poa = (const float*)Ps[w + 4];                         \
      const float* pob = (const float*)Ps[w];                             \
      _Pragma("unroll")                                                   \
      for (int g = 0; g < 16; g++) {                                      \
        oa[g] = oa[g] * a0 + poa[g * 64 + l] * a1;                        \
        ob[g] = ob[g] * a0 + pob[g * 64 + l] * a1;                        \
      }                                                                   \
      l_ln = l_ln * a0 + l1 * a1;                                         \
      WRITE_OUT();                                                        \
    }                                                                     \
    __builtin_amdgcn_s_barrier();                                         \
  } while (0)

  // segment A state
  int q0w = jA * 128 + qsub * 32;
  const unsigned short* qp = qkv + (size_t)(b * TT + q0w + lq) * N3 + head * HSS + hl * 8;
  bf16x8 qf0 = ld8(qp), qf1 = ld8(qp + 16), qf2 = ld8(qp + 32), qf3 = ld8(qp + 48);
  float m_s = -INFINITY, l_ln = 0.f;
  f32x16 oa = z16(), ob = z16();
  char* prow = (char*)Ps[w] + lq * 128;

  STAGE(0, 0);
  int cur = 0;

  for (int seq = 0; seq < NT; ++seq) {
    if (seq == mA) {
      MERGE();  // finalize segment A; y written by par0
      q0w = jB * 128 + qsub * 32;
      const unsigned short* qp2 = qkv + (size_t)(b * TT + q0w + lq) * N3 + head * HSS + hl * 8;
      qf0 = ld8(qp2); qf1 = ld8(qp2 + 16); qf2 = ld8(qp2 + 32); qf3 = ld8(qp2 + 48);
      m_s = -INFINITY; l_ln = 0.f;
      oa = z16(); ob = z16();
    }

    const int kvt = (seq < mA) ? seq : (seq - mA);
    if (seq + 1 < NT) {
      int s2 = seq + 1;
      int kvt2 = (s2 < mA) ? s2 : (s2 - mA);
      int nxt = (cur == 2) ? 0 : cur + 1;
      STAGE(nxt, kvt2);
      __builtin_amdgcn_sched_barrier(0);
      asm volatile("s_waitcnt vmcnt(4)" ::: "memory");
    } else {
      asm volatile("s_waitcnt vmcnt(0)" ::: "memory");
    }
    __builtin_amdgcn_s_barrier();
    __builtin_amdgcn_sched_barrier(0);

    const int mybuf = cur;
    cur = (cur == 2) ? 0 : cur + 1;

    const int kv0w = kvt * 128 + 64 * par;
    if (kv0w > q0w + 31) continue;  // fully-masked for this wave (barriers done)

    const unsigned short* Kb = Ks[mybuf];
    const unsigned short* Vb = Vs[mybuf];

    // QK^T swapped: sa/sb hold S^T[kv][q=lq], kv=kv0w+(g&3)+8*(g>>2)+4*hl (+32 sb)
    const char* krA = (const char*)Kb + (64 * par + lq) * 128;
    const char* krB = krA + 32 * 128;
    f32x16 sa = z16(), sb = z16();
    __builtin_amdgcn_s_setprio(1);
    {
      bf16x8 ka, kb8;
      ka = ld8((const unsigned short*)(krA + offs[0]));
      kb8 = ld8((const unsigned short*)(krB + offs[0]));
      sa = mfma32(ka, qf0, sa); sb = mfma32(kb8, qf0, sb);
      ka = ld8((const unsigned short*)(krA + offs[1]));
      kb8 = ld8((const unsigned short*)(krB + offs[1]));
      sa = mfma32(ka, qf1, sa); sb = mfma32(kb8, qf1, sb);
      ka = ld8((const unsigned short*)(krA + offs[2]));
      kb8 = ld8((const unsigned short*)(krB + offs[2]));
      sa = mfma32(ka, qf2, sa); sb = mfma32(kb8, qf2, sb);
      ka = ld8((const unsigned short*)(krA + offs[3]));
      kb8 = ld8((const unsigned short*)(krB + offs[3]));
      sa = mfma32(ka, qf3, sa); sb = mfma32(kb8, qf3, sb);
    }
    __builtin_amdgcn_s_setprio(0);

    // causal mask near the diagonal
    if (kv0w + 63 > q0w) {
      const int q = q0w + lq;
#pragma unroll
      for (int g = 0; g < 16; g++) {
        int kvl = kv0w + (g & 3) + 8 * (g >> 2) + 4 * hl;
        if (kvl > q) sa[g] = -INFINITY;
        if (kvl + 32 > q) sb[g] = -INFINITY;
      }
    }

    // per-lane max: depth-6 tree, then cross-half combine
    float m8t[8];
#pragma unroll
    for (int g = 0; g < 8; g++)
      m8t[g] = fmaxf(fmaxf(sa[g], sa[g + 8]), fmaxf(sb[g], sb[g + 8]));
    float m4a = fmaxf(fmaxf(m8t[0], m8t[1]), fmaxf(m8t[2], m8t[3]));
    float m4b = fmaxf(fmaxf(m8t[4], m8t[5]), fmaxf(m8t[6], m8t[7]));
    float tmax = fmaxf(m4a, m4b);
    tmax = fmaxf(tmax, __shfl_xor(tmax, 32));

    if (!__all(tmax <= m_s + THR)) {
      float m_new = fmaxf(m_s, tmax);
      float alpha = __builtin_amdgcn_exp2f((m_s - m_new) * cexp);
      l_ln *= alpha;
#pragma unroll
      for (int g = 0; g < 16; g++) { oa[g] *= alpha; ob[g] *= alpha; }
      m_s = m_new;
    }

    // exp in place; tree-sum into l (depth-6 instead of 32-deep serial adds)
    const float mc = m_s * cexp;
#pragma unroll
    for (int g = 0; g < 16; g++) {
      sa[g] = __builtin_amdgcn_exp2f(__builtin_fmaf(sa[g], cexp, -mc));
      sb[g] = __builtin_amdgcn_exp2f(__builtin_fmaf(sb[g], cexp, -mc));
    }
    {
      float s8t[8];
#pragma unroll
      for (int g = 0; g < 8; g++)
        s8t[g] = (sa[g] + sa[g + 8]) + (sb[g] + sb[g + 8]);
      float s4a = (s8t[0] + s8t[1]) + (s8t[2] + s8t[3]);
      float s4b = (s8t[4] + s8t[5]) + (s8t[6] + s8t[7]);
      l_ln += s4a + s4b;
    }

    // P -> LDS bounce (wave-private)
#pragma unroll
    for (int u2 = 0; u2 < 4; u2++) {
      bf16x4 w0, w1;
#pragma unroll
      for (int r = 0; r < 4; r++) { w0[r] = (__bf16)sa[4 * u2 + r]; w1[r] = (__bf16)sb[4 * u2 + r]; }
      *(bf16x4*)(prow + ((16 * u2 + 8 * hl) ^ myswz)) = w0;
      *(bf16x4*)(prow + ((64 + 16 * u2 + 8 * hl) ^ myswz)) = w1;
    }
    asm volatile("s_waitcnt lgkmcnt(0)" ::: "memory");
    __builtin_amdgcn_sched_barrier(0);
    bf16x8 pf0 = ld8((const unsigned short*)(prow + offs[0]));
    bf16x8 pf1 = ld8((const unsigned short*)(prow + offs[1]));
    bf16x8 pf2 = ld8((const unsigned short*)(prow + offs[2]));
    bf16x8 pf3 = ld8((const unsigned short*)(prow + offs[3]));

    // PV on this wave's V subtile (kv parity half)
    const char* vrA = (const char*)Vb + par * 8192 + lq * 128;
    const char* vrB = vrA + 32 * 128;
    __builtin_amdgcn_s_setprio(1);
    {
      bf16x8 va, vb8;
      va = ld8((const unsigned short*)(vrA + offs[0]));
      vb8 = ld8((const unsigned short*)(vrB + offs[0]));
      oa = mfma32(va, pf0, oa); ob = mfma32(vb8, pf0, ob);
      va = ld8((const unsigned short*)(vrA + offs[1]));
      vb8 = ld8((const unsigned short*)(vrB + offs[1]));
      oa = mfma32(va, pf1, oa); ob = mfma32(vb8, pf1, ob);
      va = ld8((const unsigned short*)(vrA + offs[2]));
      vb8 = ld8((const unsigned short*)(vrB + offs[2]));
      oa = mfma32(va, pf2, oa); ob = mfma32(vb8, pf2, ob);
      va = ld8((const unsigned short*)(vrA + offs[3]));
      vb8 = ld8((const unsigned short*)(vrB + offs[3]));
      oa = mfma32(va, pf3, oa); ob = mfma32(vb8, pf3, ob);
    }
    __builtin_amdgcn_s_setprio(0);
  }

  MERGE();  // finalize segment B
#undef STAGE
#undef WRITE_OUT
#undef MERGE
#undef SWZ
}

extern "C" void kernel_launch(void* const* d_in, const int* in_sizes, int n_in,
                              void* d_out, int out_size, void* d_ws, size_t ws_size,
                              hipStream_t stream) {
  const float* x = (const float*)d_in[0];
  const float* W_attn = (const float*)d_in[1];
  const float* b_attn = (const float*)d_in[2];
  const float* W_proj = (const float*)d_in[3];
  const float* b_proj = (const float*)d_in[4];

  char* ws = (char*)d_ws;
  unsigned short* xb   = (unsigned short*)(ws);                       // 8 MB
  unsigned short* wabt = (unsigned short*)(ws + 8388608);             // 6 MB  [3072][1024]
  unsigned short* wpbt = (unsigned short*)(ws + 14680064);            // 2 MB  [1024][1024]
  unsigned short* qkvb = (unsigned short*)(ws + 16777216);            // 24 MB [4096][3072]
  unsigned short* vt   = (unsigned short*)(ws + 41943040);            // 8 MB  [32][64][2048]
  unsigned short* yb   = (unsigned short*)(ws + 50331648);            // 8 MB  [4096][1024]

  k_prep<<<dim3(5120), 256, 0, stream>>>(x, W_attn, W_proj, xb, wabt, wpbt);
  // QKV: M=4096, N=3072 -> 32x24 tiles = 768 blocks; XCD grid 4x2, region 8Mx12N
  // V third written transposed to vt directly (k_vt fused into epilogue).
  k_gemm<1><<<dim3(768), 512, 0, stream>>>(xb, wabt, b_attn, qkvb, vt, N3, CC, 8, 12, 2);
  k_attn<<<dim3(256), 512, 0, stream>>>(qkvb, vt, yb);
  // proj: 128x64 tiles -> 32x16 = 512 blocks, 4 blocks/CU
  k_gemmp<<<dim3(512), 256, 0, stream>>>(yb, wpbt, b_proj, (float*)d_out);
}